// Round 11
// baseline (424.472 us; speedup 1.0000x reference)
//
#include <hip/hip_runtime.h>
#include <math.h>

#define N_PTS 65536
#define DIM   64
#define K_CL  128
#define EPSV  1e-8f
#define CAP   8192

// ---------------- ws layout (bytes) ----------------
// 0        : fill_acc[128] float
// 1024     : pred_x[N] int
// 263168   : idx_x[128*CAP] int
// 4457472  : idx_t[128*CAP] int
// 8651776  : count_x[128], +512: count_t[128]
// 8652800  : parts[8192] float
// 8685568  : sumw[N] float
// 8947712  : inv_sumw[N] float
// 9209856  : pred_enc[N] u64
// 9732096  : offc[128] int (per-cluster float-offset into gxT/gtT)
// 9732608  : gxT  (64*(N+4K) floats = 16908288 B)
// 26640896 : gtT  (same)
// 43549184 : end  -> transpose path needs ws_size >= this

#define GT_FLOATS (DIM * (N_PTS + 4 * K_CL))
#define WS_NEEDED 43549184ull

__global__ __launch_bounds__(256) void k_init(
    float* __restrict__ fill_acc, float* __restrict__ sumw,
    unsigned long long* __restrict__ pred_enc) {
  const int i = blockIdx.x * 256 + threadIdx.x;
  if (i < K_CL) fill_acc[i] = 0.0f;
  sumw[i] = 0.0f;
  pred_enc[i] = 0xFFFFFFFFFFFFFFFFull;
}

// Block-level K-split: block (pb, kb) handles 256 points x 32 clusters.
// jbase block-uniform -> centers scalarized (s_load). No min-wave floor
// (R9 lesson: occupancy floors spill xr[64]).
__global__ __launch_bounds__(256) void k_dist1(
    const float* __restrict__ x, const float* __restrict__ centers,
    float* __restrict__ sumw, unsigned long long* __restrict__ pred_enc)
{
  __shared__ float csq[32];
  const int kb    = blockIdx.x & 3;
  const int pb    = blockIdx.x >> 2;
  const int jbase = kb << 5;
  const int tid   = threadIdx.x;
  const int p     = pb * 256 + tid;

  if (tid < 32) {
    const float* cp = centers + (jbase + tid) * DIM;
    float s = 0.0f;
    #pragma unroll 8
    for (int d = 0; d < DIM; ++d) { float v = cp[d]; s += v * v; }
    csq[tid] = s;
  }

  float xr[DIM];
  const float4* xp = reinterpret_cast<const float4*>(x + (size_t)p * DIM);
  #pragma unroll
  for (int q = 0; q < DIM / 4; ++q) {
    float4 v = xp[q];
    xr[4 * q + 0] = v.x; xr[4 * q + 1] = v.y;
    xr[4 * q + 2] = v.z; xr[4 * q + 3] = v.w;
  }
  float xsq = 0.0f;
  #pragma unroll
  for (int d = 0; d < DIM; ++d) xsq += xr[d] * xr[d];
  __syncthreads();

  float sw = 0.0f, best = INFINITY;
  int   bj = jbase;
  #pragma unroll 2
  for (int jj = 0; jj < 32; ++jj) {
    const int j = jbase + jj;
    const float* cp = centers + j * DIM;
    float d0 = 0.f, d1 = 0.f, d2a = 0.f, d3 = 0.f;
    #pragma unroll
    for (int d = 0; d < DIM; d += 4) {
      d0  += xr[d + 0] * cp[d + 0];
      d1  += xr[d + 1] * cp[d + 1];
      d2a += xr[d + 2] * cp[d + 2];
      d3  += xr[d + 3] * cp[d + 3];
    }
    float dot  = (d0 + d1) + (d2a + d3);
    float dsq  = xsq + csq[jj] - 2.0f * dot;
    float dist = sqrtf(fmaxf(dsq, 0.0f));
    sw += 1.0f / (dist + EPSV);
    if (dist < best) { best = dist; bj = j; }
  }
  atomicAdd(&sumw[p], sw);
  const unsigned long long enc =
      ((unsigned long long)__float_as_uint(best) << 32) | (unsigned int)bj;
  atomicMin(&pred_enc[p], enc);
}

__global__ __launch_bounds__(256) void k_pred(
    const unsigned long long* __restrict__ pred_enc,
    const float* __restrict__ sumw,
    int* __restrict__ pred_x, float* __restrict__ inv_sumw) {
  const int p = blockIdx.x * 256 + threadIdx.x;
  pred_x[p]   = (int)(pred_enc[p] & 0xFFFFFFFFull);
  inv_sumw[p] = 1.0f / sumw[p];
}

__global__ __launch_bounds__(256) void k_dist2(
    const float* __restrict__ x, const float* __restrict__ centers,
    const float* __restrict__ inv_sumw, float* __restrict__ fill_acc)
{
  __shared__ float csq[32];
  __shared__ float fl[32];
  const int kb    = blockIdx.x & 3;
  const int pb    = blockIdx.x >> 2;
  const int jbase = kb << 5;
  const int tid   = threadIdx.x;
  const int p     = pb * 256 + tid;

  if (tid < 32) {
    const float* cp = centers + (jbase + tid) * DIM;
    float s = 0.0f;
    #pragma unroll 8
    for (int d = 0; d < DIM; ++d) { float v = cp[d]; s += v * v; }
    csq[tid] = s;
    fl[tid] = 0.0f;
  }

  float xr[DIM];
  const float4* xp = reinterpret_cast<const float4*>(x + (size_t)p * DIM);
  #pragma unroll
  for (int q = 0; q < DIM / 4; ++q) {
    float4 v = xp[q];
    xr[4 * q + 0] = v.x; xr[4 * q + 1] = v.y;
    xr[4 * q + 2] = v.z; xr[4 * q + 3] = v.w;
  }
  float xsq = 0.0f;
  #pragma unroll
  for (int d = 0; d < DIM; ++d) xsq += xr[d] * xr[d];
  const float invv = inv_sumw[p];
  __syncthreads();

  #pragma unroll 2
  for (int jj = 0; jj < 32; ++jj) {
    const float* cp = centers + (jbase + jj) * DIM;
    float d0 = 0.f, d1 = 0.f, d2a = 0.f, d3 = 0.f;
    #pragma unroll
    for (int d = 0; d < DIM; d += 4) {
      d0  += xr[d + 0] * cp[d + 0];
      d1  += xr[d + 1] * cp[d + 1];
      d2a += xr[d + 2] * cp[d + 2];
      d3  += xr[d + 3] * cp[d + 3];
    }
    float dot  = (d0 + d1) + (d2a + d3);
    float dsq  = xsq + csq[jj] - 2.0f * dot;
    float dist = sqrtf(fmaxf(dsq, 0.0f));
    float wn   = (1.0f / (dist + EPSV)) * invv;
    wn += __shfl_down(wn, 32);
    wn += __shfl_down(wn, 16);
    wn += __shfl_down(wn, 8);
    wn += __shfl_down(wn, 4);
    wn += __shfl_down(wn, 2);
    wn += __shfl_down(wn, 1);
    if ((tid & 63) == 0) atomicAdd(&fl[jj], wn);
  }
  __syncthreads();
  if (tid < 32) atomicAdd(&fill_acc[jbase + tid], fl[tid]);
}

// stable member-list build, two-phase (1 barrier):
__global__ __launch_bounds__(1024) void k_scatter(
    const int* __restrict__ pred_x, const int* __restrict__ pred_t,
    int* __restrict__ idx_x, int* __restrict__ idx_t,
    int* __restrict__ count_x, int* __restrict__ count_t)
{
  const int c    = blockIdx.x >> 1;
  const int side = blockIdx.x & 1;
  const int* __restrict__ pred = side ? pred_t : pred_x;
  int* __restrict__ out = side ? idx_t : idx_x;
  int* __restrict__ cnt = side ? count_t : count_x;

  __shared__ int wsum[16];
  const int tid = threadIdx.x, lane = tid & 63, w = tid >> 6;
  const int beg = w * 4096;

  int cw = 0;
  for (int s = 0; s < 4096; s += 64) {
    const bool m = (pred[beg + s + lane] == c);
    cw += __popcll(__ballot(m));
  }
  if (lane == 0) wsum[w] = cw;
  __syncthreads();
  int base = 0, tot = 0;
  #pragma unroll
  for (int k = 0; k < 16; ++k) { int v = wsum[k]; tot += v; if (k < w) base += v; }

  int run = base;
  for (int s = 0; s < 4096; s += 64) {
    const int i = beg + s + lane;
    const bool m = (pred[i] == c);
    unsigned long long bal = __ballot(m);
    int lp = __popcll(bal & ((1ull << lane) - 1ull));
    if (m) { int pos = run + lp; if (pos < CAP) out[c * CAP + pos] = i; }
    run += __popcll(bal);
  }
  if (tid == 0) cnt[c] = tot;
}

// per-cluster column-arena offsets: exclusive scan of 64 * roundup4(m)
__global__ __launch_bounds__(128) void k_offsets(
    const int* __restrict__ count_x, const int* __restrict__ count_t,
    int* __restrict__ offc)
{
  __shared__ int sm[128];
  const int tid = threadIdx.x;
  const int m  = min(min(count_x[tid], CAP), min(count_t[tid], CAP));
  const int sz = ((m + 3) & ~3) * DIM;
  sm[tid] = sz;
  __syncthreads();
  for (int s = 1; s < 128; s <<= 1) {
    int v = (tid >= s) ? sm[tid - s] : 0;
    __syncthreads();
    sm[tid] += v;
    __syncthreads();
  }
  offc[tid] = sm[tid] - sz;
}

// Gather + transpose: one wave per (side, cluster, 64-member chunk). Lane =
// member: reads its full 256B row (100% line utilization), writes transposed
// columns (fixed d across lanes -> consecutive r -> coalesced stores).
__global__ __launch_bounds__(256) void k_gather_t(
    const float* __restrict__ x, const float* __restrict__ t,
    const int* __restrict__ idx_x, const int* __restrict__ idx_t,
    const int* __restrict__ count_x, const int* __restrict__ count_t,
    const int* __restrict__ offc,
    float* __restrict__ gxT, float* __restrict__ gtT)
{
  const int wid  = blockIdx.x * 4 + (threadIdx.x >> 6);
  const int lane = threadIdx.x & 63;
  const int side = wid >> 14;           // 16384 waves per side
  const int c    = (wid >> 7) & 127;
  const int q    = wid & 127;
  const int m = min(min(count_x[c], CAP), min(count_t[c], CAP));
  if (q * 64 >= m) return;
  const int r  = q * 64 + lane;
  const int mp = (m + 3) & ~3;
  const float* __restrict__ src = side ? t : x;
  const int*   __restrict__ idx = side ? idx_t : idx_x;
  float* __restrict__ dst = (side ? gtT : gxT) + offc[c];
  if (r < m) {
    const float4* rp =
        reinterpret_cast<const float4*>(src + (size_t)idx[c * CAP + r] * DIM);
    float v[DIM];
    #pragma unroll
    for (int qq = 0; qq < DIM / 4; ++qq) {
      float4 f = rp[qq];
      v[4*qq+0]=f.x; v[4*qq+1]=f.y; v[4*qq+2]=f.z; v[4*qq+3]=f.w;
    }
    #pragma unroll
    for (int d = 0; d < DIM; ++d) dst[(size_t)d * mp + r] = v[d];
  }
}

// ---- in-register bitonic helpers ----
__device__ __forceinline__ void ce(float& a, float& b, bool up) {
  float lo = fminf(a, b), hi = fmaxf(a, b);
  a = up ? lo : hi;
  b = up ? hi : lo;
}

__device__ __forceinline__ void merge8(float* v, bool up) {
  ce(v[0],v[4],up); ce(v[1],v[5],up); ce(v[2],v[6],up); ce(v[3],v[7],up);
  ce(v[0],v[2],up); ce(v[1],v[3],up); ce(v[4],v[6],up); ce(v[5],v[7],up);
  ce(v[0],v[1],up); ce(v[2],v[3],up); ce(v[4],v[5],up); ce(v[6],v[7],up);
}

__device__ __forceinline__ void sort8(float* v, bool up8) {
  ce(v[0],v[1],true );  ce(v[2],v[3],false); ce(v[4],v[5],true );  ce(v[6],v[7],false);
  ce(v[0],v[2],true );  ce(v[1],v[3],true );  ce(v[4],v[6],false); ce(v[5],v[7],false);
  ce(v[0],v[1],true );  ce(v[2],v[3],true );  ce(v[4],v[5],false); ce(v[6],v[7],false);
  merge8(v, up8);
}

__device__ __forceinline__ void merge16(float* v, bool up) {
  #pragma unroll
  for (int e = 0; e < 8; ++e) ce(v[e], v[e + 8], up);
  merge8(v, up);
  merge8(v + 8, up);
}

__device__ __forceinline__ void sort16(float* v, bool up16) {
  sort8(v, true);
  sort8(v + 8, false);
  merge16(v, up16);
}

__device__ __forceinline__ void stage_tail(float va[8], float vb[8],
                                           int ib, int k, bool up) {
  for (int j = (k >> 1) > 256 ? 256 : (k >> 1); j >= 8; j >>= 1) {
    const int  jl = j >> 3;
    const bool low = ((ib & j) == 0);
    const bool tm  = (up == low);
    #pragma unroll
    for (int e = 0; e < 8; ++e) {
      float p = __shfl_xor(va[e], jl, 64);
      va[e] = tm ? fminf(va[e], p) : fmaxf(va[e], p);
      float q = __shfl_xor(vb[e], jl, 64);
      vb[e] = tm ? fminf(vb[e], q) : fmaxf(vb[e], q);
    }
  }
  merge8(va, up);
  merge8(vb, up);
}

__device__ __forceinline__ void stage_tail16(float va[16], float vb[16],
                                             int ib, int k, bool up) {
  for (int j = (k >> 1) > 512 ? 512 : (k >> 1); j >= 16; j >>= 1) {
    const int  jl = j >> 4;
    const bool low = ((ib & j) == 0);
    const bool tm  = (up == low);
    #pragma unroll
    for (int e = 0; e < 16; ++e) {
      float p = __shfl_xor(va[e], jl, 64);
      va[e] = tm ? fminf(va[e], p) : fmaxf(va[e], p);
      float q = __shfl_xor(vb[e], jl, 64);
      vb[e] = tm ? fminf(vb[e], q) : fmaxf(vb[e], q);
    }
  }
  merge16(va, up);
  merge16(vb, up);
}

__device__ __forceinline__ void load8c(const float* __restrict__ col,
                                       int ib, int m, float v[8]) {
  if (ib + 7 < m) {
    #pragma unroll
    for (int q = 0; q < 2; ++q) {
      float4 f = *(const float4*)&col[ib + 4 * q];
      v[4*q+0]=f.x; v[4*q+1]=f.y; v[4*q+2]=f.z; v[4*q+3]=f.w;
    }
  } else {
    #pragma unroll
    for (int e = 0; e < 8; ++e) v[e] = (ib + e < m) ? col[ib + e] : INFINITY;
  }
}

__device__ __forceinline__ void load16c(const float* __restrict__ col,
                                        int ib, int m, float v[16]) {
  if (ib + 15 < m) {
    #pragma unroll
    for (int q = 0; q < 4; ++q) {
      float4 f = *(const float4*)&col[ib + 4 * q];
      v[4*q+0]=f.x; v[4*q+1]=f.y; v[4*q+2]=f.z; v[4*q+3]=f.w;
    }
  } else {
    #pragma unroll
    for (int e = 0; e < 16; ++e) v[e] = (ib + e < m) ? col[ib + e] : INFINITY;
  }
}

// Unified W1 from coalesced column arenas. Blocks [0,8192): per-task role
// for m>1024; blocks [8192,9216): 8 wave-tasks each (m<=1024).
__global__ __launch_bounds__(512, 4) void k_w1_cols(
    const float* __restrict__ gxT, const float* __restrict__ gtT,
    const int* __restrict__ offc,
    const int* __restrict__ count_x, const int* __restrict__ count_t,
    float* __restrict__ parts)
{
  __shared__ float sa[8192];
  __shared__ float sb[8192];
  __shared__ float red[8];
  const int tid = threadIdx.x;

  if (blockIdx.x < 8192) {
    const int task = blockIdx.x;
    const int c = task >> 6, d = task & 63;
    const int m = min(min(count_x[c], CAP), min(count_t[c], CAP));
    if (m <= 1024) return;
    const int mp = (m + 3) & ~3;
    const float* colx = gxT + offc[c] + (size_t)d * mp;
    const float* colt = gtT + offc[c] + (size_t)d * mp;
    int P = 2048;
    while (P < m) P <<= 1;

    const int ib  = tid << 4;
    const bool active = (ib < P);
    float va[16], vb[16];
    if (active) {
      load16c(colx, ib, m, va);
      load16c(colt, ib, m, vb);
      const bool u16 = ((ib & 16) == 0);
      sort16(va, u16);
      sort16(vb, u16);
    }

    for (int k = 32; k <= P; k <<= 1) {
      const bool up = ((ib & k) == 0);
      for (int j = k >> 1; j >= 1024; j >>= 1) {
        __syncthreads();
        if (active) {
          #pragma unroll
          for (int q = 0; q < 4; ++q) {
            *(float4*)&sa[ib + 4*q] = make_float4(va[4*q],va[4*q+1],va[4*q+2],va[4*q+3]);
            *(float4*)&sb[ib + 4*q] = make_float4(vb[4*q],vb[4*q+1],vb[4*q+2],vb[4*q+3]);
          }
        }
        __syncthreads();
        if (active) {
          const int pi = ib ^ j;
          const bool tm = (up == ((ib & j) == 0));
          #pragma unroll
          for (int q = 0; q < 4; ++q) {
            float4 A = *(const float4*)&sa[pi + 4*q];
            float4 B = *(const float4*)&sb[pi + 4*q];
            va[4*q+0] = tm ? fminf(va[4*q+0],A.x) : fmaxf(va[4*q+0],A.x);
            va[4*q+1] = tm ? fminf(va[4*q+1],A.y) : fmaxf(va[4*q+1],A.y);
            va[4*q+2] = tm ? fminf(va[4*q+2],A.z) : fmaxf(va[4*q+2],A.z);
            va[4*q+3] = tm ? fminf(va[4*q+3],A.w) : fmaxf(va[4*q+3],A.w);
            vb[4*q+0] = tm ? fminf(vb[4*q+0],B.x) : fmaxf(vb[4*q+0],B.x);
            vb[4*q+1] = tm ? fminf(vb[4*q+1],B.y) : fmaxf(vb[4*q+1],B.y);
            vb[4*q+2] = tm ? fminf(vb[4*q+2],B.z) : fmaxf(vb[4*q+2],B.z);
            vb[4*q+3] = tm ? fminf(vb[4*q+3],B.w) : fmaxf(vb[4*q+3],B.w);
          }
        }
      }
      if (active) stage_tail16(va, vb, ib, k, up);
    }

    float s = 0.0f;
    if (active) {
      #pragma unroll
      for (int e = 0; e < 16; ++e)
        if (ib + e < m) s += fabsf(va[e] - vb[e]);
    }
    #pragma unroll
    for (int off = 32; off > 0; off >>= 1) s += __shfl_down(s, off);
    __syncthreads();
    if ((tid & 63) == 0) red[tid >> 6] = s;
    __syncthreads();
    if (tid == 0) {
      float tot = 0.0f;
      #pragma unroll
      for (int w = 0; w < 8; ++w) tot += red[w];
      parts[task] = tot / (float)(m * DIM);
    }
  } else {
    const int task = (blockIdx.x - 8192) * 8 + (tid >> 6);
    const int lane = tid & 63;
    const int c = task >> 6, d = task & 63;
    const int m = min(min(count_x[c], CAP), min(count_t[c], CAP));
    if (m > 1024) return;
    if (m == 0) { if (lane == 0) parts[task] = 0.0f; return; }
    const int mp = (m + 3) & ~3;
    const float* colx = gxT + offc[c] + (size_t)d * mp;
    const float* colt = gtT + offc[c] + (size_t)d * mp;

    float s = 0.0f;
    if (m <= 512) {
      int P = 8;
      while (P < m) P <<= 1;
      const int ib = lane << 3;
      float va[8], vb[8];
      load8c(colx, ib, m, va);
      load8c(colt, ib, m, vb);
      const bool u8 = ((ib & 8) == 0);
      sort8(va, u8);
      sort8(vb, u8);
      for (int k = 16; k <= P; k <<= 1)
        stage_tail(va, vb, ib, k, ((ib & k) == 0));
      #pragma unroll
      for (int e = 0; e < 8; ++e)
        if (ib + e < m) s += fabsf(va[e] - vb[e]);
    } else {
      const int ib = lane << 4;
      float va[16], vb[16];
      load16c(colx, ib, m, va);
      load16c(colt, ib, m, vb);
      const bool u16 = ((ib & 16) == 0);
      sort16(va, u16);
      sort16(vb, u16);
      for (int k = 32; k <= 1024; k <<= 1)
        stage_tail16(va, vb, ib, k, ((ib & k) == 0));
      #pragma unroll
      for (int e = 0; e < 16; ++e)
        if (ib + e < m) s += fabsf(va[e] - vb[e]);
    }
    #pragma unroll
    for (int off = 32; off > 0; off >>= 1) s += __shfl_down(s, off);
    if (lane == 0) parts[task] = s / (float)(m * DIM);
  }
}

// Fallback (ws too small for arenas): R10 idx-gather version.
__global__ __launch_bounds__(512, 4) void k_w1_idx(
    const float* __restrict__ x, const float* __restrict__ t,
    const int* __restrict__ idx_x, const int* __restrict__ idx_t,
    const int* __restrict__ count_x, const int* __restrict__ count_t,
    float* __restrict__ parts)
{
  __shared__ float sa[8192];
  __shared__ float sb[8192];
  __shared__ float red[8];
  const int tid = threadIdx.x;

  if (blockIdx.x < 8192) {
    const int task = blockIdx.x;
    const int c = task >> 6, d = task & 63;
    const int m = min(min(count_x[c], CAP), min(count_t[c], CAP));
    if (m <= 1024) return;
    int P = 2048;
    while (P < m) P <<= 1;

    const int ib  = tid << 4;
    const bool active = (ib < P);
    const int gb  = c * CAP + ib;
    float va[16], vb[16];
    if (active) {
      #pragma unroll
      for (int e = 0; e < 16; ++e) {
        if (ib + e < m) {
          va[e] = x[(size_t)idx_x[gb + e] * DIM + d];
          vb[e] = t[(size_t)idx_t[gb + e] * DIM + d];
        } else { va[e] = INFINITY; vb[e] = INFINITY; }
      }
      const bool u16 = ((ib & 16) == 0);
      sort16(va, u16);
      sort16(vb, u16);
    }

    for (int k = 32; k <= P; k <<= 1) {
      const bool up = ((ib & k) == 0);
      for (int j = k >> 1; j >= 1024; j >>= 1) {
        __syncthreads();
        if (active) {
          #pragma unroll
          for (int q = 0; q < 4; ++q) {
            *(float4*)&sa[ib + 4*q] = make_float4(va[4*q],va[4*q+1],va[4*q+2],va[4*q+3]);
            *(float4*)&sb[ib + 4*q] = make_float4(vb[4*q],vb[4*q+1],vb[4*q+2],vb[4*q+3]);
          }
        }
        __syncthreads();
        if (active) {
          const int pi = ib ^ j;
          const bool tm = (up == ((ib & j) == 0));
          #pragma unroll
          for (int q = 0; q < 4; ++q) {
            float4 A = *(const float4*)&sa[pi + 4*q];
            float4 B = *(const float4*)&sb[pi + 4*q];
            va[4*q+0] = tm ? fminf(va[4*q+0],A.x) : fmaxf(va[4*q+0],A.x);
            va[4*q+1] = tm ? fminf(va[4*q+1],A.y) : fmaxf(va[4*q+1],A.y);
            va[4*q+2] = tm ? fminf(va[4*q+2],A.z) : fmaxf(va[4*q+2],A.z);
            va[4*q+3] = tm ? fminf(va[4*q+3],A.w) : fmaxf(va[4*q+3],A.w);
            vb[4*q+0] = tm ? fminf(vb[4*q+0],B.x) : fmaxf(vb[4*q+0],B.x);
            vb[4*q+1] = tm ? fminf(vb[4*q+1],B.y) : fmaxf(vb[4*q+1],B.y);
            vb[4*q+2] = tm ? fminf(vb[4*q+2],B.z) : fmaxf(vb[4*q+2],B.z);
            vb[4*q+3] = tm ? fminf(vb[4*q+3],B.w) : fmaxf(vb[4*q+3],B.w);
          }
        }
      }
      if (active) stage_tail16(va, vb, ib, k, up);
    }

    float s = 0.0f;
    if (active) {
      #pragma unroll
      for (int e = 0; e < 16; ++e)
        if (ib + e < m) s += fabsf(va[e] - vb[e]);
    }
    #pragma unroll
    for (int off = 32; off > 0; off >>= 1) s += __shfl_down(s, off);
    __syncthreads();
    if ((tid & 63) == 0) red[tid >> 6] = s;
    __syncthreads();
    if (tid == 0) {
      float tot = 0.0f;
      #pragma unroll
      for (int w = 0; w < 8; ++w) tot += red[w];
      parts[task] = tot / (float)(m * DIM);
    }
  } else {
    const int task = (blockIdx.x - 8192) * 8 + (tid >> 6);
    const int lane = tid & 63;
    const int c = task >> 6, d = task & 63;
    const int m = min(min(count_x[c], CAP), min(count_t[c], CAP));
    if (m > 1024) return;
    if (m == 0) { if (lane == 0) parts[task] = 0.0f; return; }

    float s = 0.0f;
    if (m <= 512) {
      int P = 8;
      while (P < m) P <<= 1;
      const int ib = lane << 3;
      const int gb = c * CAP + ib;
      float va[8], vb[8];
      #pragma unroll
      for (int e = 0; e < 8; ++e) {
        if (ib + e < m) {
          va[e] = x[(size_t)idx_x[gb + e] * DIM + d];
          vb[e] = t[(size_t)idx_t[gb + e] * DIM + d];
        } else { va[e] = INFINITY; vb[e] = INFINITY; }
      }
      const bool u8 = ((ib & 8) == 0);
      sort8(va, u8);
      sort8(vb, u8);
      for (int k = 16; k <= P; k <<= 1)
        stage_tail(va, vb, ib, k, ((ib & k) == 0));
      #pragma unroll
      for (int e = 0; e < 8; ++e)
        if (ib + e < m) s += fabsf(va[e] - vb[e]);
    } else {
      const int ib = lane << 4;
      const int gb = c * CAP + ib;
      float va[16], vb[16];
      #pragma unroll
      for (int e = 0; e < 16; ++e) {
        if (ib + e < m) {
          va[e] = x[(size_t)idx_x[gb + e] * DIM + d];
          vb[e] = t[(size_t)idx_t[gb + e] * DIM + d];
        } else { va[e] = INFINITY; vb[e] = INFINITY; }
      }
      const bool u16 = ((ib & 16) == 0);
      sort16(va, u16);
      sort16(vb, u16);
      for (int k = 32; k <= 1024; k <<= 1)
        stage_tail16(va, vb, ib, k, ((ib & k) == 0));
      #pragma unroll
      for (int e = 0; e < 16; ++e)
        if (ib + e < m) s += fabsf(va[e] - vb[e]);
    }
    #pragma unroll
    for (int off = 32; off > 0; off >>= 1) s += __shfl_down(s, off);
    if (lane == 0) parts[task] = s / (float)(m * DIM);
  }
}

__global__ __launch_bounds__(1024) void k_final(
    const float* __restrict__ fill_acc, const float* __restrict__ ft,
    const float* __restrict__ parts, float* __restrict__ out)
{
  __shared__ float red[16];
  const int tid = threadIdx.x;
  float s = 0.0f;
  #pragma unroll
  for (int i = 0; i < 8; ++i) s += parts[tid + i * 1024];
  if (tid < K_CL) {
    float v = fill_acc[tid] * (1.0f / (float)N_PTS) - ft[tid];
    s += v * v * (1.0f / (float)K_CL);
  }
  #pragma unroll
  for (int off = 32; off > 0; off >>= 1) s += __shfl_down(s, off);
  if ((tid & 63) == 0) red[tid >> 6] = s;
  __syncthreads();
  if (tid == 0) {
    float tot = 0.0f;
    #pragma unroll
    for (int w = 0; w < 16; ++w) tot += red[w];
    out[0] = tot;
  }
}

extern "C" void kernel_launch(void* const* d_in, const int* in_sizes, int n_in,
                              void* d_out, int out_size, void* d_ws, size_t ws_size,
                              hipStream_t stream)
{
  (void)in_sizes; (void)n_in; (void)out_size;
  const float* x      = (const float*)d_in[0];
  const float* target = (const float*)d_in[1];
  const float* cc     = (const float*)d_in[2];
  const int*   pred_t = (const int*)d_in[3];
  const float* ft     = (const float*)d_in[4];
  float* out = (float*)d_out;

  char* ws = (char*)d_ws;
  float* fill_acc = (float*)(ws + 0);
  int*   pred_x   = (int*)(ws + 1024);
  int*   idx_x    = (int*)(ws + 263168);
  int*   idx_t    = (int*)(ws + 4457472);
  int*   count_x  = (int*)(ws + 8651776);
  int*   count_t  = (int*)(ws + 8651776 + 512);
  float* parts    = (float*)(ws + 8652800);
  float* sumw     = (float*)(ws + 8685568);
  float* inv_sumw = (float*)(ws + 8947712);
  unsigned long long* pred_enc = (unsigned long long*)(ws + 9209856);
  int*   offc     = (int*)(ws + 9732096);
  float* gxT      = (float*)(ws + 9732608);
  float* gtT      = (float*)(ws + 26640896);

  k_init<<<N_PTS / 256, 256, 0, stream>>>(fill_acc, sumw, pred_enc);
  k_dist1<<<N_PTS / 256 * 4, 256, 0, stream>>>(x, cc, sumw, pred_enc);
  k_pred<<<N_PTS / 256, 256, 0, stream>>>(pred_enc, sumw, pred_x, inv_sumw);
  k_dist2<<<N_PTS / 256 * 4, 256, 0, stream>>>(x, cc, inv_sumw, fill_acc);
  k_scatter<<<K_CL * 2, 1024, 0, stream>>>(pred_x, pred_t, idx_x, idx_t,
                                           count_x, count_t);
  if (ws_size >= WS_NEEDED) {
    k_offsets<<<1, 128, 0, stream>>>(count_x, count_t, offc);
    k_gather_t<<<8192, 256, 0, stream>>>(x, target, idx_x, idx_t,
                                         count_x, count_t, offc, gxT, gtT);
    k_w1_cols<<<8192 + 1024, 512, 0, stream>>>(gxT, gtT, offc,
                                               count_x, count_t, parts);
  } else {
    k_w1_idx<<<8192 + 1024, 512, 0, stream>>>(x, target, idx_x, idx_t,
                                              count_x, count_t, parts);
  }
  k_final<<<1, 1024, 0, stream>>>(fill_acc, ft, parts, out);
}

// Round 12
// 411.185 us; speedup vs baseline: 1.0323x; 1.0323x over previous
//
#include <hip/hip_runtime.h>
#include <math.h>

#define N_PTS 65536
#define DIM   64
#define K_CL  128
#define EPSV  1e-8f
#define CAP   8192

// ---------------- ws layout (bytes) ----------------
// 0        : fill_acc[128] float
// 1024     : pred_x[N] int
// 263168   : idx_x[128*CAP] int
// 4457472  : idx_t[128*CAP] int
// 8651776  : count_x[128], +512: count_t[128]
// 8652800  : parts[8192] float
// 8685568  : sumw[N] float
// 8947712  : inv_sumw[N] float
// 9209856  : pred_enc[N] u64
// 9732096  : offc[128] int
// 9732608  : gxT  (16908288 B)
// 26640896 : gtT  (16908288 B)
// 43549184 : end

#define WS_NEEDED 43549184ull

__global__ __launch_bounds__(256) void k_init(
    float* __restrict__ fill_acc, float* __restrict__ sumw,
    unsigned long long* __restrict__ pred_enc) {
  const int i = blockIdx.x * 256 + threadIdx.x;
  if (i < K_CL) fill_acc[i] = 0.0f;
  sumw[i] = 0.0f;
  pred_enc[i] = 0xFFFFFFFFFFFFFFFFull;
}

// Block-level K-split; jbase block-uniform -> centers scalarized (s_load).
__global__ __launch_bounds__(256) void k_dist1(
    const float* __restrict__ x, const float* __restrict__ centers,
    float* __restrict__ sumw, unsigned long long* __restrict__ pred_enc)
{
  __shared__ float csq[32];
  const int kb    = blockIdx.x & 3;
  const int pb    = blockIdx.x >> 2;
  const int jbase = kb << 5;
  const int tid   = threadIdx.x;
  const int p     = pb * 256 + tid;

  if (tid < 32) {
    const float* cp = centers + (jbase + tid) * DIM;
    float s = 0.0f;
    #pragma unroll 8
    for (int d = 0; d < DIM; ++d) { float v = cp[d]; s += v * v; }
    csq[tid] = s;
  }

  float xr[DIM];
  const float4* xp = reinterpret_cast<const float4*>(x + (size_t)p * DIM);
  #pragma unroll
  for (int q = 0; q < DIM / 4; ++q) {
    float4 v = xp[q];
    xr[4 * q + 0] = v.x; xr[4 * q + 1] = v.y;
    xr[4 * q + 2] = v.z; xr[4 * q + 3] = v.w;
  }
  float xsq = 0.0f;
  #pragma unroll
  for (int d = 0; d < DIM; ++d) xsq += xr[d] * xr[d];
  __syncthreads();

  float sw = 0.0f, best = INFINITY;
  int   bj = jbase;
  #pragma unroll 2
  for (int jj = 0; jj < 32; ++jj) {
    const int j = jbase + jj;
    const float* cp = centers + j * DIM;
    float d0 = 0.f, d1 = 0.f, d2a = 0.f, d3 = 0.f;
    #pragma unroll
    for (int d = 0; d < DIM; d += 4) {
      d0  += xr[d + 0] * cp[d + 0];
      d1  += xr[d + 1] * cp[d + 1];
      d2a += xr[d + 2] * cp[d + 2];
      d3  += xr[d + 3] * cp[d + 3];
    }
    float dot  = (d0 + d1) + (d2a + d3);
    float dsq  = xsq + csq[jj] - 2.0f * dot;
    float dist = sqrtf(fmaxf(dsq, 0.0f));
    sw += 1.0f / (dist + EPSV);
    if (dist < best) { best = dist; bj = j; }
  }
  atomicAdd(&sumw[p], sw);
  const unsigned long long enc =
      ((unsigned long long)__float_as_uint(best) << 32) | (unsigned int)bj;
  atomicMin(&pred_enc[p], enc);
}

__global__ __launch_bounds__(256) void k_pred(
    const unsigned long long* __restrict__ pred_enc,
    const float* __restrict__ sumw,
    int* __restrict__ pred_x, float* __restrict__ inv_sumw) {
  const int p = blockIdx.x * 256 + threadIdx.x;
  pred_x[p]   = (int)(pred_enc[p] & 0xFFFFFFFFull);
  inv_sumw[p] = 1.0f / sumw[p];
}

__global__ __launch_bounds__(256) void k_dist2(
    const float* __restrict__ x, const float* __restrict__ centers,
    const float* __restrict__ inv_sumw, float* __restrict__ fill_acc)
{
  __shared__ float csq[32];
  __shared__ float fl[32];
  const int kb    = blockIdx.x & 3;
  const int pb    = blockIdx.x >> 2;
  const int jbase = kb << 5;
  const int tid   = threadIdx.x;
  const int p     = pb * 256 + tid;

  if (tid < 32) {
    const float* cp = centers + (jbase + tid) * DIM;
    float s = 0.0f;
    #pragma unroll 8
    for (int d = 0; d < DIM; ++d) { float v = cp[d]; s += v * v; }
    csq[tid] = s;
    fl[tid] = 0.0f;
  }

  float xr[DIM];
  const float4* xp = reinterpret_cast<const float4*>(x + (size_t)p * DIM);
  #pragma unroll
  for (int q = 0; q < DIM / 4; ++q) {
    float4 v = xp[q];
    xr[4 * q + 0] = v.x; xr[4 * q + 1] = v.y;
    xr[4 * q + 2] = v.z; xr[4 * q + 3] = v.w;
  }
  float xsq = 0.0f;
  #pragma unroll
  for (int d = 0; d < DIM; ++d) xsq += xr[d] * xr[d];
  const float invv = inv_sumw[p];
  __syncthreads();

  #pragma unroll 2
  for (int jj = 0; jj < 32; ++jj) {
    const float* cp = centers + (jbase + jj) * DIM;
    float d0 = 0.f, d1 = 0.f, d2a = 0.f, d3 = 0.f;
    #pragma unroll
    for (int d = 0; d < DIM; d += 4) {
      d0  += xr[d + 0] * cp[d + 0];
      d1  += xr[d + 1] * cp[d + 1];
      d2a += xr[d + 2] * cp[d + 2];
      d3  += xr[d + 3] * cp[d + 3];
    }
    float dot  = (d0 + d1) + (d2a + d3);
    float dsq  = xsq + csq[jj] - 2.0f * dot;
    float dist = sqrtf(fmaxf(dsq, 0.0f));
    float wn   = (1.0f / (dist + EPSV)) * invv;
    wn += __shfl_down(wn, 32);
    wn += __shfl_down(wn, 16);
    wn += __shfl_down(wn, 8);
    wn += __shfl_down(wn, 4);
    wn += __shfl_down(wn, 2);
    wn += __shfl_down(wn, 1);
    if ((tid & 63) == 0) atomicAdd(&fl[jj], wn);
  }
  __syncthreads();
  if (tid < 32) atomicAdd(&fill_acc[jbase + tid], fl[tid]);
}

// stable member-list build, two-phase (1 barrier):
__global__ __launch_bounds__(1024) void k_scatter(
    const int* __restrict__ pred_x, const int* __restrict__ pred_t,
    int* __restrict__ idx_x, int* __restrict__ idx_t,
    int* __restrict__ count_x, int* __restrict__ count_t)
{
  const int c    = blockIdx.x >> 1;
  const int side = blockIdx.x & 1;
  const int* __restrict__ pred = side ? pred_t : pred_x;
  int* __restrict__ out = side ? idx_t : idx_x;
  int* __restrict__ cnt = side ? count_t : count_x;

  __shared__ int wsum[16];
  const int tid = threadIdx.x, lane = tid & 63, w = tid >> 6;
  const int beg = w * 4096;

  int cw = 0;
  for (int s = 0; s < 4096; s += 64) {
    const bool m = (pred[beg + s + lane] == c);
    cw += __popcll(__ballot(m));
  }
  if (lane == 0) wsum[w] = cw;
  __syncthreads();
  int base = 0, tot = 0;
  #pragma unroll
  for (int k = 0; k < 16; ++k) { int v = wsum[k]; tot += v; if (k < w) base += v; }

  int run = base;
  for (int s = 0; s < 4096; s += 64) {
    const int i = beg + s + lane;
    const bool m = (pred[i] == c);
    unsigned long long bal = __ballot(m);
    int lp = __popcll(bal & ((1ull << lane) - 1ull));
    if (m) { int pos = run + lp; if (pos < CAP) out[c * CAP + pos] = i; }
    run += __popcll(bal);
  }
  if (tid == 0) cnt[c] = tot;
}

// per-cluster column-arena offsets: exclusive scan of 64 * roundup4(m)
__global__ __launch_bounds__(128) void k_offsets(
    const int* __restrict__ count_x, const int* __restrict__ count_t,
    int* __restrict__ offc)
{
  __shared__ int sm[128];
  const int tid = threadIdx.x;
  const int m  = min(min(count_x[tid], CAP), min(count_t[tid], CAP));
  const int sz = ((m + 3) & ~3) * DIM;
  sm[tid] = sz;
  __syncthreads();
  for (int s = 1; s < 128; s <<= 1) {
    int v = (tid >= s) ? sm[tid - s] : 0;
    __syncthreads();
    sm[tid] += v;
    __syncthreads();
  }
  offc[tid] = sm[tid] - sz;
}

// Gather + transpose: lane = member, reads full 256B row, writes transposed
// coalesced columns.
__global__ __launch_bounds__(256) void k_gather_t(
    const float* __restrict__ x, const float* __restrict__ t,
    const int* __restrict__ idx_x, const int* __restrict__ idx_t,
    const int* __restrict__ count_x, const int* __restrict__ count_t,
    const int* __restrict__ offc,
    float* __restrict__ gxT, float* __restrict__ gtT)
{
  const int wid  = blockIdx.x * 4 + (threadIdx.x >> 6);
  const int lane = threadIdx.x & 63;
  const int side = wid >> 14;
  const int c    = (wid >> 7) & 127;
  const int q    = wid & 127;
  const int m = min(min(count_x[c], CAP), min(count_t[c], CAP));
  if (q * 64 >= m) return;
  const int r  = q * 64 + lane;
  const int mp = (m + 3) & ~3;
  const float* __restrict__ src = side ? t : x;
  const int*   __restrict__ idx = side ? idx_t : idx_x;
  float* __restrict__ dst = (side ? gtT : gxT) + offc[c];
  if (r < m) {
    const float4* rp =
        reinterpret_cast<const float4*>(src + (size_t)idx[c * CAP + r] * DIM);
    float v[DIM];
    #pragma unroll
    for (int qq = 0; qq < DIM / 4; ++qq) {
      float4 f = rp[qq];
      v[4*qq+0]=f.x; v[4*qq+1]=f.y; v[4*qq+2]=f.z; v[4*qq+3]=f.w;
    }
    #pragma unroll
    for (int d = 0; d < DIM; ++d) dst[(size_t)d * mp + r] = v[d];
  }
}

// ---- in-register bitonic helpers ----
__device__ __forceinline__ void ce(float& a, float& b, bool up) {
  float lo = fminf(a, b), hi = fmaxf(a, b);
  a = up ? lo : hi;
  b = up ? hi : lo;
}

__device__ __forceinline__ void merge8(float* v, bool up) {
  ce(v[0],v[4],up); ce(v[1],v[5],up); ce(v[2],v[6],up); ce(v[3],v[7],up);
  ce(v[0],v[2],up); ce(v[1],v[3],up); ce(v[4],v[6],up); ce(v[5],v[7],up);
  ce(v[0],v[1],up); ce(v[2],v[3],up); ce(v[4],v[5],up); ce(v[6],v[7],up);
}

__device__ __forceinline__ void sort8(float* v, bool up8) {
  ce(v[0],v[1],true );  ce(v[2],v[3],false); ce(v[4],v[5],true );  ce(v[6],v[7],false);
  ce(v[0],v[2],true );  ce(v[1],v[3],true );  ce(v[4],v[6],false); ce(v[5],v[7],false);
  ce(v[0],v[1],true );  ce(v[2],v[3],true );  ce(v[4],v[5],false); ce(v[6],v[7],false);
  merge8(v, up8);
}

__device__ __forceinline__ void merge16(float* v, bool up) {
  #pragma unroll
  for (int e = 0; e < 8; ++e) ce(v[e], v[e + 8], up);
  merge8(v, up);
  merge8(v + 8, up);
}

__device__ __forceinline__ void sort16(float* v, bool up16) {
  sort8(v, true);
  sort8(v + 8, false);
  merge16(v, up16);
}

// dual-array V=8 stage (wave kernel, constant k -> fully unrolled)
__device__ __forceinline__ void stage_pair8(float va[8], float vb[8],
                                            int ib, int k, bool up) {
  #pragma unroll
  for (int j = (k >> 1) > 256 ? 256 : (k >> 1); j >= 8; j >>= 1) {
    const int  jl = j >> 3;
    const bool tm = (up == ((ib & j) == 0));
    #pragma unroll
    for (int e = 0; e < 8; ++e) {
      float p = __shfl_xor(va[e], jl, 64);
      va[e] = tm ? fminf(va[e], p) : fmaxf(va[e], p);
      float q = __shfl_xor(vb[e], jl, 64);
      vb[e] = tm ? fminf(vb[e], q) : fmaxf(vb[e], q);
    }
  }
  merge8(va, up);
  merge8(vb, up);
}

// dual-array V=16 stage (wave kernel m<=1024 path)
__device__ __forceinline__ void stage_pair16(float va[16], float vb[16],
                                             int ib, int k, bool up) {
  #pragma unroll
  for (int j = (k >> 1) > 512 ? 512 : (k >> 1); j >= 16; j >>= 1) {
    const int  jl = j >> 4;
    const bool tm = (up == ((ib & j) == 0));
    #pragma unroll
    for (int e = 0; e < 16; ++e) {
      float p = __shfl_xor(va[e], jl, 64);
      va[e] = tm ? fminf(va[e], p) : fmaxf(va[e], p);
      float q = __shfl_xor(vb[e], jl, 64);
      vb[e] = tm ? fminf(vb[e], q) : fmaxf(vb[e], q);
    }
  }
  merge16(va, up);
  merge16(vb, up);
}

// single-array V=16 stage: shfl j=min(k/2,512)..16 then merge16
__device__ __forceinline__ void stage_one16(float v[16], int ib, int k, bool up) {
  #pragma unroll
  for (int j = (k >> 1) > 512 ? 512 : (k >> 1); j >= 16; j >>= 1) {
    const int  jl = j >> 4;
    const bool tm = (up == ((ib & j) == 0));
    #pragma unroll
    for (int e = 0; e < 16; ++e) {
      float p = __shfl_xor(v[e], jl, 64);
      v[e] = tm ? fminf(v[e], p) : fmaxf(v[e], p);
    }
  }
  merge16(v, up);
}

__device__ __forceinline__ void load8c(const float* __restrict__ col,
                                       int ib, int m, float v[8]) {
  if (ib + 7 < m) {
    #pragma unroll
    for (int q = 0; q < 2; ++q) {
      float4 f = *(const float4*)&col[ib + 4 * q];
      v[4*q+0]=f.x; v[4*q+1]=f.y; v[4*q+2]=f.z; v[4*q+3]=f.w;
    }
  } else {
    #pragma unroll
    for (int e = 0; e < 8; ++e) v[e] = (ib + e < m) ? col[ib + e] : INFINITY;
  }
}

__device__ __forceinline__ void load16c(const float* __restrict__ col,
                                        int ib, int m, float v[16]) {
  if (ib + 15 < m) {
    #pragma unroll
    for (int q = 0; q < 4; ++q) {
      float4 f = *(const float4*)&col[ib + 4 * q];
      v[4*q+0]=f.x; v[4*q+1]=f.y; v[4*q+2]=f.z; v[4*q+3]=f.w;
    }
  } else {
    #pragma unroll
    for (int e = 0; e < 16; ++e) v[e] = (ib + e < m) ? col[ib + e] : INFINITY;
  }
}

// full P-sort of one column into registers; LDS (sa) used only for j>=1024.
// P compile-time -> every loop unrolls -> no scratch spill (R11 lesson:
// runtime P demoted va/vb to scratch, 60 MB WRITE_SIZE).
template<int P>
__device__ __forceinline__ void sort_col(float v[16], int ib, bool act,
                                         const float* __restrict__ col,
                                         int m, float* __restrict__ sa) {
  if (act) {
    load16c(col, ib, m, v);
    sort16(v, ((ib & 16) == 0));
    #pragma unroll
    for (int k = 32; k <= 1024; k <<= 1)
      stage_one16(v, ib, k, ((ib & k) == 0));
  }
  #pragma unroll
  for (int k = 2048; k <= P; k <<= 1) {
    const bool up = ((ib & k) == 0);
    #pragma unroll
    for (int j = k >> 1; j >= 1024; j >>= 1) {
      __syncthreads();                     // prior phase's reads complete
      if (act) {
        #pragma unroll
        for (int q = 0; q < 4; ++q)
          *(float4*)&sa[ib + 4*q] =
              make_float4(v[4*q], v[4*q+1], v[4*q+2], v[4*q+3]);
      }
      __syncthreads();
      if (act) {
        const int pi = ib ^ j;
        const bool tm = (up == ((ib & j) == 0));
        #pragma unroll
        for (int q = 0; q < 4; ++q) {
          float4 A = *(const float4*)&sa[pi + 4*q];
          v[4*q+0] = tm ? fminf(v[4*q+0],A.x) : fmaxf(v[4*q+0],A.x);
          v[4*q+1] = tm ? fminf(v[4*q+1],A.y) : fmaxf(v[4*q+1],A.y);
          v[4*q+2] = tm ? fminf(v[4*q+2],A.z) : fmaxf(v[4*q+2],A.z);
          v[4*q+3] = tm ? fminf(v[4*q+3],A.w) : fmaxf(v[4*q+3],A.w);
        }
      }
    }
    if (act) stage_one16(v, ib, k, up);
  }
}

template<int P>
__device__ __forceinline__ float task_body(const float* colx, const float* colt,
                                           int m, int tid, float* sa) {
  const int ib = tid << 4;
  const bool act = (ib < P);
  float va[16], vb[16];
  sort_col<P>(va, ib, act, colx, m, sa);     // sorted A stays in regs
  sort_col<P>(vb, ib, act, colt, m, sa);
  float s = 0.0f;
  if (act) {
    #pragma unroll
    for (int e = 0; e < 16; ++e)
      if (ib + e < m) s += fabsf(va[e] - vb[e]);
  }
  return s;
}

// Task kernel: m > 1024, one block per (cluster, feature). Block-uniform
// branch selects the compile-time P instance. Single 32 KB LDS buffer.
__global__ __launch_bounds__(512) void k_w1_task(
    const float* __restrict__ gxT, const float* __restrict__ gtT,
    const int* __restrict__ offc,
    const int* __restrict__ count_x, const int* __restrict__ count_t,
    float* __restrict__ parts)
{
  __shared__ float sa[8192];   // 32 KB
  __shared__ float red[8];
  const int tid  = threadIdx.x;
  const int task = blockIdx.x;
  const int c = task >> 6, d = task & 63;
  const int m = min(min(count_x[c], CAP), min(count_t[c], CAP));
  if (m <= 1024) return;
  const int mp = (m + 3) & ~3;
  const float* colx = gxT + offc[c] + (size_t)d * mp;
  const float* colt = gtT + offc[c] + (size_t)d * mp;

  float s;
  if (m <= 2048)      s = task_body<2048>(colx, colt, m, tid, sa);
  else if (m <= 4096) s = task_body<4096>(colx, colt, m, tid, sa);
  else                s = task_body<8192>(colx, colt, m, tid, sa);

  #pragma unroll
  for (int off = 32; off > 0; off >>= 1) s += __shfl_down(s, off);
  __syncthreads();
  if ((tid & 63) == 0) red[tid >> 6] = s;
  __syncthreads();
  if (tid == 0) {
    float tot = 0.0f;
    #pragma unroll
    for (int w = 0; w < 8; ++w) tot += red[w];
    parts[task] = tot / (float)(m * DIM);
  }
}

// Wave kernel: m <= 1024, 4 wave-tasks per 256-thr block, NO LDS ->
// occupancy limited only by VGPRs. Constant P=512 (V=8) / P=1024 (V=16).
__global__ __launch_bounds__(256) void k_w1_wave(
    const float* __restrict__ gxT, const float* __restrict__ gtT,
    const int* __restrict__ offc,
    const int* __restrict__ count_x, const int* __restrict__ count_t,
    float* __restrict__ parts)
{
  const int task = blockIdx.x * 4 + (threadIdx.x >> 6);
  const int lane = threadIdx.x & 63;
  const int c = task >> 6, d = task & 63;
  const int m = min(min(count_x[c], CAP), min(count_t[c], CAP));
  if (m > 1024) return;
  if (m == 0) { if (lane == 0) parts[task] = 0.0f; return; }
  const int mp = (m + 3) & ~3;
  const float* colx = gxT + offc[c] + (size_t)d * mp;
  const float* colt = gtT + offc[c] + (size_t)d * mp;

  float s = 0.0f;
  if (m <= 512) {
    const int ib = lane << 3;
    float va[8], vb[8];
    load8c(colx, ib, m, va);
    load8c(colt, ib, m, vb);
    const bool u8 = ((ib & 8) == 0);
    sort8(va, u8);
    sort8(vb, u8);
    #pragma unroll
    for (int k = 16; k <= 512; k <<= 1)
      stage_pair8(va, vb, ib, k, ((ib & k) == 0));
    #pragma unroll
    for (int e = 0; e < 8; ++e)
      if (ib + e < m) s += fabsf(va[e] - vb[e]);
  } else {
    const int ib = lane << 4;
    float va[16], vb[16];
    load16c(colx, ib, m, va);
    load16c(colt, ib, m, vb);
    const bool u16 = ((ib & 16) == 0);
    sort16(va, u16);
    sort16(vb, u16);
    #pragma unroll
    for (int k = 32; k <= 1024; k <<= 1)
      stage_pair16(va, vb, ib, k, ((ib & k) == 0));
    #pragma unroll
    for (int e = 0; e < 16; ++e)
      if (ib + e < m) s += fabsf(va[e] - vb[e]);
  }
  #pragma unroll
  for (int off = 32; off > 0; off >>= 1) s += __shfl_down(s, off);
  if (lane == 0) parts[task] = s / (float)(m * DIM);
}

__global__ __launch_bounds__(1024) void k_final(
    const float* __restrict__ fill_acc, const float* __restrict__ ft,
    const float* __restrict__ parts, float* __restrict__ out)
{
  __shared__ float red[16];
  const int tid = threadIdx.x;
  float s = 0.0f;
  #pragma unroll
  for (int i = 0; i < 8; ++i) s += parts[tid + i * 1024];
  if (tid < K_CL) {
    float v = fill_acc[tid] * (1.0f / (float)N_PTS) - ft[tid];
    s += v * v * (1.0f / (float)K_CL);
  }
  #pragma unroll
  for (int off = 32; off > 0; off >>= 1) s += __shfl_down(s, off);
  if ((tid & 63) == 0) red[tid >> 6] = s;
  __syncthreads();
  if (tid == 0) {
    float tot = 0.0f;
    #pragma unroll
    for (int w = 0; w < 16; ++w) tot += red[w];
    out[0] = tot;
  }
}

extern "C" void kernel_launch(void* const* d_in, const int* in_sizes, int n_in,
                              void* d_out, int out_size, void* d_ws, size_t ws_size,
                              hipStream_t stream)
{
  (void)in_sizes; (void)n_in; (void)out_size; (void)ws_size;
  const float* x      = (const float*)d_in[0];
  const float* target = (const float*)d_in[1];
  const float* cc     = (const float*)d_in[2];
  const int*   pred_t = (const int*)d_in[3];
  const float* ft     = (const float*)d_in[4];
  float* out = (float*)d_out;

  char* ws = (char*)d_ws;
  float* fill_acc = (float*)(ws + 0);
  int*   pred_x   = (int*)(ws + 1024);
  int*   idx_x    = (int*)(ws + 263168);
  int*   idx_t    = (int*)(ws + 4457472);
  int*   count_x  = (int*)(ws + 8651776);
  int*   count_t  = (int*)(ws + 8651776 + 512);
  float* parts    = (float*)(ws + 8652800);
  float* sumw     = (float*)(ws + 8685568);
  float* inv_sumw = (float*)(ws + 8947712);
  unsigned long long* pred_enc = (unsigned long long*)(ws + 9209856);
  int*   offc     = (int*)(ws + 9732096);
  float* gxT      = (float*)(ws + 9732608);
  float* gtT      = (float*)(ws + 26640896);

  k_init<<<N_PTS / 256, 256, 0, stream>>>(fill_acc, sumw, pred_enc);
  k_dist1<<<N_PTS / 256 * 4, 256, 0, stream>>>(x, cc, sumw, pred_enc);
  k_pred<<<N_PTS / 256, 256, 0, stream>>>(pred_enc, sumw, pred_x, inv_sumw);
  k_dist2<<<N_PTS / 256 * 4, 256, 0, stream>>>(x, cc, inv_sumw, fill_acc);
  k_scatter<<<K_CL * 2, 1024, 0, stream>>>(pred_x, pred_t, idx_x, idx_t,
                                           count_x, count_t);
  k_offsets<<<1, 128, 0, stream>>>(count_x, count_t, offc);
  k_gather_t<<<8192, 256, 0, stream>>>(x, target, idx_x, idx_t,
                                       count_x, count_t, offc, gxT, gtT);
  k_w1_task<<<K_CL * DIM, 512, 0, stream>>>(gxT, gtT, offc,
                                            count_x, count_t, parts);
  k_w1_wave<<<K_CL * DIM / 4, 256, 0, stream>>>(gxT, gtT, offc,
                                                count_x, count_t, parts);
  k_final<<<1, 1024, 0, stream>>>(fill_acc, ft, parts, out);
}

// Round 13
// 342.370 us; speedup vs baseline: 1.2398x; 1.2010x over previous
//
#include <hip/hip_runtime.h>
#include <math.h>

#define N_PTS 65536
#define DIM   64
#define K_CL  128
#define EPSV  1e-8f
#define CAP   8192

// ---------------- ws layout (bytes) ----------------
// 0        : fill_acc[128] float
// 1024     : pred_x[N] int
// 263168   : idx_x[128*CAP] int
// 4457472  : idx_t[128*CAP] int
// 8651776  : count_x[128], +512: count_t[128]
// 8652800  : parts[8192] float
// 8685568  : sumw[N] float
// 8947712  : inv_sumw[N] float
// 9209856  : pred_enc[N] u64
// 9732096  : offc[128] int
// 9732608  : gxT (16908288 B)  -- ALSO w[128][N] (32 MB) before k_gather_t
// 26640896 : gtT (16908288 B)
// 43549184 : end

__global__ __launch_bounds__(256) void k_init(
    float* __restrict__ fill_acc, float* __restrict__ sumw,
    unsigned long long* __restrict__ pred_enc) {
  const int i = blockIdx.x * 256 + threadIdx.x;
  if (i < K_CL) fill_acc[i] = 0.0f;
  sumw[i] = 0.0f;
  pred_enc[i] = 0xFFFFFFFFFFFFFFFFull;
}

// Block-level K-split; jbase block-uniform -> centers scalarized (s_load).
// Stores w[j][p] (coalesced) so the normalize pass needn't recompute.
__global__ __launch_bounds__(256) void k_dist1(
    const float* __restrict__ x, const float* __restrict__ centers,
    float* __restrict__ sumw, unsigned long long* __restrict__ pred_enc,
    float* __restrict__ w)
{
  __shared__ float csq[32];
  const int kb    = blockIdx.x & 3;
  const int pb    = blockIdx.x >> 2;
  const int jbase = kb << 5;
  const int tid   = threadIdx.x;
  const int p     = pb * 256 + tid;

  if (tid < 32) {
    const float* cp = centers + (jbase + tid) * DIM;
    float s = 0.0f;
    #pragma unroll 8
    for (int d = 0; d < DIM; ++d) { float v = cp[d]; s += v * v; }
    csq[tid] = s;
  }

  float xr[DIM];
  const float4* xp = reinterpret_cast<const float4*>(x + (size_t)p * DIM);
  #pragma unroll
  for (int q = 0; q < DIM / 4; ++q) {
    float4 v = xp[q];
    xr[4 * q + 0] = v.x; xr[4 * q + 1] = v.y;
    xr[4 * q + 2] = v.z; xr[4 * q + 3] = v.w;
  }
  float xsq = 0.0f;
  #pragma unroll
  for (int d = 0; d < DIM; ++d) xsq += xr[d] * xr[d];
  __syncthreads();

  float sw = 0.0f, best = INFINITY;
  int   bj = jbase;
  #pragma unroll 2
  for (int jj = 0; jj < 32; ++jj) {
    const int j = jbase + jj;
    const float* cp = centers + j * DIM;
    float d0 = 0.f, d1 = 0.f, d2a = 0.f, d3 = 0.f;
    #pragma unroll
    for (int d = 0; d < DIM; d += 4) {
      d0  += xr[d + 0] * cp[d + 0];
      d1  += xr[d + 1] * cp[d + 1];
      d2a += xr[d + 2] * cp[d + 2];
      d3  += xr[d + 3] * cp[d + 3];
    }
    float dot  = (d0 + d1) + (d2a + d3);
    float dsq  = xsq + csq[jj] - 2.0f * dot;
    float dist = sqrtf(fmaxf(dsq, 0.0f));
    float ww   = 1.0f / (dist + EPSV);
    w[(size_t)j * N_PTS + p] = ww;
    sw += ww;
    if (dist < best) { best = dist; bj = j; }
  }
  atomicAdd(&sumw[p], sw);
  const unsigned long long enc =
      ((unsigned long long)__float_as_uint(best) << 32) | (unsigned int)bj;
  atomicMin(&pred_enc[p], enc);
}

__global__ __launch_bounds__(256) void k_pred(
    const unsigned long long* __restrict__ pred_enc,
    const float* __restrict__ sumw,
    int* __restrict__ pred_x, float* __restrict__ inv_sumw) {
  const int p = blockIdx.x * 256 + threadIdx.x;
  pred_x[p]   = (int)(pred_enc[p] & 0xFFFFFFFFull);
  inv_sumw[p] = 1.0f / sumw[p];
}

// Streaming normalize+reduce: block (j, seg of 8192 points). Reads stored
// w, multiplies by inv_sumw, tree-reduces, one atomic per block.
__global__ __launch_bounds__(256) void k_fill(
    const float* __restrict__ w, const float* __restrict__ inv_sumw,
    float* __restrict__ fill_acc)
{
  __shared__ float red[4];
  const int j    = blockIdx.x >> 3;
  const int seg  = blockIdx.x & 7;
  const int tid  = threadIdx.x;
  const float4* wj = reinterpret_cast<const float4*>(
      w + (size_t)j * N_PTS + seg * 8192);
  const float4* iv = reinterpret_cast<const float4*>(
      inv_sumw + seg * 8192);
  float s = 0.0f;
  #pragma unroll
  for (int q = 0; q < 8; ++q) {
    const int e = q * 256 + tid;
    float4 a = wj[e];
    float4 b = iv[e];
    s += a.x * b.x + a.y * b.y + a.z * b.z + a.w * b.w;
  }
  #pragma unroll
  for (int off = 32; off > 0; off >>= 1) s += __shfl_down(s, off);
  if ((tid & 63) == 0) red[tid >> 6] = s;
  __syncthreads();
  if (tid == 0)
    atomicAdd(&fill_acc[j], red[0] + red[1] + red[2] + red[3]);
}

// stable member-list build, two-phase (1 barrier):
__global__ __launch_bounds__(1024) void k_scatter(
    const int* __restrict__ pred_x, const int* __restrict__ pred_t,
    int* __restrict__ idx_x, int* __restrict__ idx_t,
    int* __restrict__ count_x, int* __restrict__ count_t)
{
  const int c    = blockIdx.x >> 1;
  const int side = blockIdx.x & 1;
  const int* __restrict__ pred = side ? pred_t : pred_x;
  int* __restrict__ out = side ? idx_t : idx_x;
  int* __restrict__ cnt = side ? count_t : count_x;

  __shared__ int wsum[16];
  const int tid = threadIdx.x, lane = tid & 63, w = tid >> 6;
  const int beg = w * 4096;

  int cw = 0;
  for (int s = 0; s < 4096; s += 64) {
    const bool m = (pred[beg + s + lane] == c);
    cw += __popcll(__ballot(m));
  }
  if (lane == 0) wsum[w] = cw;
  __syncthreads();
  int base = 0, tot = 0;
  #pragma unroll
  for (int k = 0; k < 16; ++k) { int v = wsum[k]; tot += v; if (k < w) base += v; }

  int run = base;
  for (int s = 0; s < 4096; s += 64) {
    const int i = beg + s + lane;
    const bool m = (pred[i] == c);
    unsigned long long bal = __ballot(m);
    int lp = __popcll(bal & ((1ull << lane) - 1ull));
    if (m) { int pos = run + lp; if (pos < CAP) out[c * CAP + pos] = i; }
    run += __popcll(bal);
  }
  if (tid == 0) cnt[c] = tot;
}

// per-cluster column-arena offsets: exclusive scan of 64 * roundup4(m)
__global__ __launch_bounds__(128) void k_offsets(
    const int* __restrict__ count_x, const int* __restrict__ count_t,
    int* __restrict__ offc)
{
  __shared__ int sm[128];
  const int tid = threadIdx.x;
  const int m  = min(min(count_x[tid], CAP), min(count_t[tid], CAP));
  const int sz = ((m + 3) & ~3) * DIM;
  sm[tid] = sz;
  __syncthreads();
  for (int s = 1; s < 128; s <<= 1) {
    int v = (tid >= s) ? sm[tid - s] : 0;
    __syncthreads();
    sm[tid] += v;
    __syncthreads();
  }
  offc[tid] = sm[tid] - sz;
}

// Gather + transpose: lane = member, reads full 256B row, writes transposed
// coalesced columns. (Overwrites the w region -- runs after k_fill.)
__global__ __launch_bounds__(256) void k_gather_t(
    const float* __restrict__ x, const float* __restrict__ t,
    const int* __restrict__ idx_x, const int* __restrict__ idx_t,
    const int* __restrict__ count_x, const int* __restrict__ count_t,
    const int* __restrict__ offc,
    float* __restrict__ gxT, float* __restrict__ gtT)
{
  const int wid  = blockIdx.x * 4 + (threadIdx.x >> 6);
  const int lane = threadIdx.x & 63;
  const int side = wid >> 14;
  const int c    = (wid >> 7) & 127;
  const int q    = wid & 127;
  const int m = min(min(count_x[c], CAP), min(count_t[c], CAP));
  if (q * 64 >= m) return;
  const int r  = q * 64 + lane;
  const int mp = (m + 3) & ~3;
  const float* __restrict__ src = side ? t : x;
  const int*   __restrict__ idx = side ? idx_t : idx_x;
  float* __restrict__ dst = (side ? gtT : gxT) + offc[c];
  if (r < m) {
    const float4* rp =
        reinterpret_cast<const float4*>(src + (size_t)idx[c * CAP + r] * DIM);
    float v[DIM];
    #pragma unroll
    for (int qq = 0; qq < DIM / 4; ++qq) {
      float4 f = rp[qq];
      v[4*qq+0]=f.x; v[4*qq+1]=f.y; v[4*qq+2]=f.z; v[4*qq+3]=f.w;
    }
    #pragma unroll
    for (int d = 0; d < DIM; ++d) dst[(size_t)d * mp + r] = v[d];
  }
}

// ---- in-register bitonic helpers ----
__device__ __forceinline__ void ce(float& a, float& b, bool up) {
  float lo = fminf(a, b), hi = fmaxf(a, b);
  a = up ? lo : hi;
  b = up ? hi : lo;
}

__device__ __forceinline__ void merge8(float* v, bool up) {
  ce(v[0],v[4],up); ce(v[1],v[5],up); ce(v[2],v[6],up); ce(v[3],v[7],up);
  ce(v[0],v[2],up); ce(v[1],v[3],up); ce(v[4],v[6],up); ce(v[5],v[7],up);
  ce(v[0],v[1],up); ce(v[2],v[3],up); ce(v[4],v[5],up); ce(v[6],v[7],up);
}

__device__ __forceinline__ void sort8(float* v, bool up8) {
  ce(v[0],v[1],true );  ce(v[2],v[3],false); ce(v[4],v[5],true );  ce(v[6],v[7],false);
  ce(v[0],v[2],true );  ce(v[1],v[3],true );  ce(v[4],v[6],false); ce(v[5],v[7],false);
  ce(v[0],v[1],true );  ce(v[2],v[3],true );  ce(v[4],v[5],false); ce(v[6],v[7],false);
  merge8(v, up8);
}

__device__ __forceinline__ void merge16(float* v, bool up) {
  #pragma unroll
  for (int e = 0; e < 8; ++e) ce(v[e], v[e + 8], up);
  merge8(v, up);
  merge8(v + 8, up);
}

__device__ __forceinline__ void sort16(float* v, bool up16) {
  sort8(v, true);
  sort8(v + 8, false);
  merge16(v, up16);
}

__device__ __forceinline__ void stage_pair8(float va[8], float vb[8],
                                            int ib, int k, bool up) {
  #pragma unroll
  for (int j = (k >> 1) > 256 ? 256 : (k >> 1); j >= 8; j >>= 1) {
    const int  jl = j >> 3;
    const bool tm = (up == ((ib & j) == 0));
    #pragma unroll
    for (int e = 0; e < 8; ++e) {
      float p = __shfl_xor(va[e], jl, 64);
      va[e] = tm ? fminf(va[e], p) : fmaxf(va[e], p);
      float q = __shfl_xor(vb[e], jl, 64);
      vb[e] = tm ? fminf(vb[e], q) : fmaxf(vb[e], q);
    }
  }
  merge8(va, up);
  merge8(vb, up);
}

__device__ __forceinline__ void stage_pair16(float va[16], float vb[16],
                                             int ib, int k, bool up) {
  #pragma unroll
  for (int j = (k >> 1) > 512 ? 512 : (k >> 1); j >= 16; j >>= 1) {
    const int  jl = j >> 4;
    const bool tm = (up == ((ib & j) == 0));
    #pragma unroll
    for (int e = 0; e < 16; ++e) {
      float p = __shfl_xor(va[e], jl, 64);
      va[e] = tm ? fminf(va[e], p) : fmaxf(va[e], p);
      float q = __shfl_xor(vb[e], jl, 64);
      vb[e] = tm ? fminf(vb[e], q) : fmaxf(vb[e], q);
    }
  }
  merge16(va, up);
  merge16(vb, up);
}

__device__ __forceinline__ void stage_one16(float v[16], int ib, int k, bool up) {
  #pragma unroll
  for (int j = (k >> 1) > 512 ? 512 : (k >> 1); j >= 16; j >>= 1) {
    const int  jl = j >> 4;
    const bool tm = (up == ((ib & j) == 0));
    #pragma unroll
    for (int e = 0; e < 16; ++e) {
      float p = __shfl_xor(v[e], jl, 64);
      v[e] = tm ? fminf(v[e], p) : fmaxf(v[e], p);
    }
  }
  merge16(v, up);
}

__device__ __forceinline__ void load8c(const float* __restrict__ col,
                                       int ib, int m, float v[8]) {
  if (ib + 7 < m) {
    #pragma unroll
    for (int q = 0; q < 2; ++q) {
      float4 f = *(const float4*)&col[ib + 4 * q];
      v[4*q+0]=f.x; v[4*q+1]=f.y; v[4*q+2]=f.z; v[4*q+3]=f.w;
    }
  } else {
    #pragma unroll
    for (int e = 0; e < 8; ++e) v[e] = (ib + e < m) ? col[ib + e] : INFINITY;
  }
}

__device__ __forceinline__ void load16c(const float* __restrict__ col,
                                        int ib, int m, float v[16]) {
  if (ib + 15 < m) {
    #pragma unroll
    for (int q = 0; q < 4; ++q) {
      float4 f = *(const float4*)&col[ib + 4 * q];
      v[4*q+0]=f.x; v[4*q+1]=f.y; v[4*q+2]=f.z; v[4*q+3]=f.w;
    }
  } else {
    #pragma unroll
    for (int e = 0; e < 16; ++e) v[e] = (ib + e < m) ? col[ib + e] : INFINITY;
  }
}

// full P-sort of one column into registers; LDS (sa) used only for j>=1024.
// P compile-time -> all loops unroll -> no scratch spill (R11 lesson).
template<int P>
__device__ __forceinline__ void sort_col(float v[16], int ib, bool act,
                                         const float* __restrict__ col,
                                         int m, float* __restrict__ sa) {
  if (act) {
    load16c(col, ib, m, v);
    sort16(v, ((ib & 16) == 0));
    #pragma unroll
    for (int k = 32; k <= 1024; k <<= 1)
      stage_one16(v, ib, k, ((ib & k) == 0));
  }
  #pragma unroll
  for (int k = 2048; k <= P; k <<= 1) {
    const bool up = ((ib & k) == 0);
    #pragma unroll
    for (int j = k >> 1; j >= 1024; j >>= 1) {
      __syncthreads();
      if (act) {
        #pragma unroll
        for (int q = 0; q < 4; ++q)
          *(float4*)&sa[ib + 4*q] =
              make_float4(v[4*q], v[4*q+1], v[4*q+2], v[4*q+3]);
      }
      __syncthreads();
      if (act) {
        const int pi = ib ^ j;
        const bool tm = (up == ((ib & j) == 0));
        #pragma unroll
        for (int q = 0; q < 4; ++q) {
          float4 A = *(const float4*)&sa[pi + 4*q];
          v[4*q+0] = tm ? fminf(v[4*q+0],A.x) : fmaxf(v[4*q+0],A.x);
          v[4*q+1] = tm ? fminf(v[4*q+1],A.y) : fmaxf(v[4*q+1],A.y);
          v[4*q+2] = tm ? fminf(v[4*q+2],A.z) : fmaxf(v[4*q+2],A.z);
          v[4*q+3] = tm ? fminf(v[4*q+3],A.w) : fmaxf(v[4*q+3],A.w);
        }
      }
    }
    if (act) stage_one16(v, ib, k, up);
  }
}

template<int P>
__device__ __forceinline__ float task_body(const float* colx, const float* colt,
                                           int m, int tid, float* sa) {
  const int ib = tid << 4;
  const bool act = (ib < P);
  float va[16], vb[16];
  sort_col<P>(va, ib, act, colx, m, sa);     // sorted A stays in regs
  sort_col<P>(vb, ib, act, colt, m, sa);
  float s = 0.0f;
  if (act) {
    #pragma unroll
    for (int e = 0; e < 16; ++e)
      if (ib + e < m) s += fabsf(va[e] - vb[e]);
  }
  return s;
}

// Merged W1. Blocks [0,8192): task role (m>1024, compile-time P via
// block-uniform branch, 32 KB LDS). Blocks [8192,9216): 8 wave-tasks each
// (m<=1024, registers+shuffles, no barriers). Task blocks dispatch first so
// big-cluster stragglers start early; the wave flood fills the tail.
__global__ __launch_bounds__(512) void k_w1(
    const float* __restrict__ gxT, const float* __restrict__ gtT,
    const int* __restrict__ offc,
    const int* __restrict__ count_x, const int* __restrict__ count_t,
    float* __restrict__ parts)
{
  __shared__ float sa[8192];   // 32 KB
  __shared__ float red[8];
  const int tid = threadIdx.x;

  if (blockIdx.x < 8192) {
    const int task = blockIdx.x;
    const int c = task >> 6, d = task & 63;
    const int m = min(min(count_x[c], CAP), min(count_t[c], CAP));
    if (m <= 1024) return;
    const int mp = (m + 3) & ~3;
    const float* colx = gxT + offc[c] + (size_t)d * mp;
    const float* colt = gtT + offc[c] + (size_t)d * mp;

    float s;
    if (m <= 2048)      s = task_body<2048>(colx, colt, m, tid, sa);
    else if (m <= 4096) s = task_body<4096>(colx, colt, m, tid, sa);
    else                s = task_body<8192>(colx, colt, m, tid, sa);

    #pragma unroll
    for (int off = 32; off > 0; off >>= 1) s += __shfl_down(s, off);
    __syncthreads();
    if ((tid & 63) == 0) red[tid >> 6] = s;
    __syncthreads();
    if (tid == 0) {
      float tot = 0.0f;
      #pragma unroll
      for (int w = 0; w < 8; ++w) tot += red[w];
      parts[task] = tot / (float)(m * DIM);
    }
  } else {
    const int task = (blockIdx.x - 8192) * 8 + (tid >> 6);
    const int lane = tid & 63;
    const int c = task >> 6, d = task & 63;
    const int m = min(min(count_x[c], CAP), min(count_t[c], CAP));
    if (m > 1024) return;
    if (m == 0) { if (lane == 0) parts[task] = 0.0f; return; }
    const int mp = (m + 3) & ~3;
    const float* colx = gxT + offc[c] + (size_t)d * mp;
    const float* colt = gtT + offc[c] + (size_t)d * mp;

    float s = 0.0f;
    if (m <= 512) {
      const int ib = lane << 3;
      float va[8], vb[8];
      load8c(colx, ib, m, va);
      load8c(colt, ib, m, vb);
      const bool u8 = ((ib & 8) == 0);
      sort8(va, u8);
      sort8(vb, u8);
      #pragma unroll
      for (int k = 16; k <= 512; k <<= 1)
        stage_pair8(va, vb, ib, k, ((ib & k) == 0));
      #pragma unroll
      for (int e = 0; e < 8; ++e)
        if (ib + e < m) s += fabsf(va[e] - vb[e]);
    } else {
      const int ib = lane << 4;
      float va[16], vb[16];
      load16c(colx, ib, m, va);
      load16c(colt, ib, m, vb);
      const bool u16 = ((ib & 16) == 0);
      sort16(va, u16);
      sort16(vb, u16);
      #pragma unroll
      for (int k = 32; k <= 1024; k <<= 1)
        stage_pair16(va, vb, ib, k, ((ib & k) == 0));
      #pragma unroll
      for (int e = 0; e < 16; ++e)
        if (ib + e < m) s += fabsf(va[e] - vb[e]);
    }
    #pragma unroll
    for (int off = 32; off > 0; off >>= 1) s += __shfl_down(s, off);
    if (lane == 0) parts[task] = s / (float)(m * DIM);
  }
}

__global__ __launch_bounds__(1024) void k_final(
    const float* __restrict__ fill_acc, const float* __restrict__ ft,
    const float* __restrict__ parts, float* __restrict__ out)
{
  __shared__ float red[16];
  const int tid = threadIdx.x;
  float s = 0.0f;
  #pragma unroll
  for (int i = 0; i < 8; ++i) s += parts[tid + i * 1024];
  if (tid < K_CL) {
    float v = fill_acc[tid] * (1.0f / (float)N_PTS) - ft[tid];
    s += v * v * (1.0f / (float)K_CL);
  }
  #pragma unroll
  for (int off = 32; off > 0; off >>= 1) s += __shfl_down(s, off);
  if ((tid & 63) == 0) red[tid >> 6] = s;
  __syncthreads();
  if (tid == 0) {
    float tot = 0.0f;
    #pragma unroll
    for (int w = 0; w < 16; ++w) tot += red[w];
    out[0] = tot;
  }
}

extern "C" void kernel_launch(void* const* d_in, const int* in_sizes, int n_in,
                              void* d_out, int out_size, void* d_ws, size_t ws_size,
                              hipStream_t stream)
{
  (void)in_sizes; (void)n_in; (void)out_size; (void)ws_size;
  const float* x      = (const float*)d_in[0];
  const float* target = (const float*)d_in[1];
  const float* cc     = (const float*)d_in[2];
  const int*   pred_t = (const int*)d_in[3];
  const float* ft     = (const float*)d_in[4];
  float* out = (float*)d_out;

  char* ws = (char*)d_ws;
  float* fill_acc = (float*)(ws + 0);
  int*   pred_x   = (int*)(ws + 1024);
  int*   idx_x    = (int*)(ws + 263168);
  int*   idx_t    = (int*)(ws + 4457472);
  int*   count_x  = (int*)(ws + 8651776);
  int*   count_t  = (int*)(ws + 8651776 + 512);
  float* parts    = (float*)(ws + 8652800);
  float* sumw     = (float*)(ws + 8685568);
  float* inv_sumw = (float*)(ws + 8947712);
  unsigned long long* pred_enc = (unsigned long long*)(ws + 9209856);
  int*   offc     = (int*)(ws + 9732096);
  float* gxT      = (float*)(ws + 9732608);
  float* gtT      = (float*)(ws + 26640896);
  float* wmat     = (float*)(ws + 9732608);   // 32 MB, dead after k_fill

  k_init<<<N_PTS / 256, 256, 0, stream>>>(fill_acc, sumw, pred_enc);
  k_dist1<<<N_PTS / 256 * 4, 256, 0, stream>>>(x, cc, sumw, pred_enc, wmat);
  k_pred<<<N_PTS / 256, 256, 0, stream>>>(pred_enc, sumw, pred_x, inv_sumw);
  k_fill<<<K_CL * 8, 256, 0, stream>>>(wmat, inv_sumw, fill_acc);
  k_scatter<<<K_CL * 2, 1024, 0, stream>>>(pred_x, pred_t, idx_x, idx_t,
                                           count_x, count_t);
  k_offsets<<<1, 128, 0, stream>>>(count_x, count_t, offc);
  k_gather_t<<<8192, 256, 0, stream>>>(x, target, idx_x, idx_t,
                                       count_x, count_t, offc, gxT, gtT);
  k_w1<<<8192 + 1024, 512, 0, stream>>>(gxT, gtT, offc,
                                        count_x, count_t, parts);
  k_final<<<1, 1024, 0, stream>>>(fill_acc, ft, parts, out);
}

// Round 15
// 323.554 us; speedup vs baseline: 1.3119x; 1.0582x over previous
//
#include <hip/hip_runtime.h>
#include <math.h>

#define N_PTS 65536
#define DIM   64
#define K_CL  128
#define EPSV  1e-8f
#define CAP   8192

// ---------------- ws layout (bytes) ----------------
// 0        : fill_acc[128] float
// 1024     : pred_x[N] int            -> 263168
// 263168   : idx_x[128*CAP] int       -> 4457472
// 4457472  : idx_t[128*CAP] int       -> 8651776
// 8651776  : count_x[128], +512: count_t[128]
// 8652800  : parts[8192] float        -> 8685568
// 8685568  : sumw[N] float            -> 8947712
// 8947712  : inv_sumw[N] float        -> 9209856
// 9209856  : pred_enc[N] u64          -> 9734144
// 9734144  : offc[128] int            -> 9734656
// 9735168  : gxT (16908288 B)         -> 26643456   } wmat (32 MB, dead after
// 26643456 : gtT (16908288 B)         -> 43551744   } k_fill) overlays these
// NOTE: R14's bug was enc4/sumw4 aliasing wmat; reverted to atomic front-end.
// R13's latent pred_enc/gxT 1536-B overlap fixed by starting arenas at 9735168.

__global__ __launch_bounds__(256) void k_init(
    float* __restrict__ fill_acc, float* __restrict__ sumw,
    unsigned long long* __restrict__ pred_enc) {
  const int i = blockIdx.x * 256 + threadIdx.x;
  if (i < K_CL) fill_acc[i] = 0.0f;
  sumw[i] = 0.0f;
  pred_enc[i] = 0xFFFFFFFFFFFFFFFFull;
}

// Block-level K-split; jbase block-uniform -> centers scalarized (s_load).
// Writes w[j][p] (coalesced) so the normalize pass needn't recompute.
__global__ __launch_bounds__(256) void k_dist1(
    const float* __restrict__ x, const float* __restrict__ centers,
    float* __restrict__ sumw, unsigned long long* __restrict__ pred_enc,
    float* __restrict__ w)
{
  __shared__ float csq[32];
  const int kb    = blockIdx.x & 3;
  const int pb    = blockIdx.x >> 2;
  const int jbase = kb << 5;
  const int tid   = threadIdx.x;
  const int p     = pb * 256 + tid;

  if (tid < 32) {
    const float* cp = centers + (jbase + tid) * DIM;
    float s = 0.0f;
    #pragma unroll 8
    for (int d = 0; d < DIM; ++d) { float v = cp[d]; s += v * v; }
    csq[tid] = s;
  }

  float xr[DIM];
  const float4* xp = reinterpret_cast<const float4*>(x + (size_t)p * DIM);
  #pragma unroll
  for (int q = 0; q < DIM / 4; ++q) {
    float4 v = xp[q];
    xr[4 * q + 0] = v.x; xr[4 * q + 1] = v.y;
    xr[4 * q + 2] = v.z; xr[4 * q + 3] = v.w;
  }
  float xsq = 0.0f;
  #pragma unroll
  for (int d = 0; d < DIM; ++d) xsq += xr[d] * xr[d];
  __syncthreads();

  float sw = 0.0f, best = INFINITY;
  int   bj = jbase;
  #pragma unroll 2
  for (int jj = 0; jj < 32; ++jj) {
    const int j = jbase + jj;
    const float* cp = centers + j * DIM;
    float d0 = 0.f, d1 = 0.f, d2a = 0.f, d3 = 0.f;
    #pragma unroll
    for (int d = 0; d < DIM; d += 4) {
      d0  += xr[d + 0] * cp[d + 0];
      d1  += xr[d + 1] * cp[d + 1];
      d2a += xr[d + 2] * cp[d + 2];
      d3  += xr[d + 3] * cp[d + 3];
    }
    float dot  = (d0 + d1) + (d2a + d3);
    float dsq  = xsq + csq[jj] - 2.0f * dot;
    float dist = sqrtf(fmaxf(dsq, 0.0f));
    float ww   = 1.0f / (dist + EPSV);
    w[(size_t)j * N_PTS + p] = ww;
    sw += ww;
    if (dist < best) { best = dist; bj = j; }
  }
  atomicAdd(&sumw[p], sw);
  const unsigned long long enc =
      ((unsigned long long)__float_as_uint(best) << 32) | (unsigned int)bj;
  atomicMin(&pred_enc[p], enc);
}

__global__ __launch_bounds__(256) void k_pred(
    const unsigned long long* __restrict__ pred_enc,
    const float* __restrict__ sumw,
    int* __restrict__ pred_x, float* __restrict__ inv_sumw) {
  const int p = blockIdx.x * 256 + threadIdx.x;
  pred_x[p]   = (int)(pred_enc[p] & 0xFFFFFFFFull);
  inv_sumw[p] = 1.0f / sumw[p];
}

// streaming normalize+reduce: block (j, seg of 8192 points); 1 atomic/block
__global__ __launch_bounds__(256) void k_fill(
    const float* __restrict__ w, const float* __restrict__ inv_sumw,
    float* __restrict__ fill_acc)
{
  __shared__ float red[4];
  const int j    = blockIdx.x >> 3;
  const int seg  = blockIdx.x & 7;
  const int tid  = threadIdx.x;
  const float4* wj = reinterpret_cast<const float4*>(
      w + (size_t)j * N_PTS + seg * 8192);
  const float4* iv = reinterpret_cast<const float4*>(inv_sumw + seg * 8192);
  float s = 0.0f;
  #pragma unroll
  for (int q = 0; q < 8; ++q) {
    const int e = q * 256 + tid;
    float4 a = wj[e];
    float4 b = iv[e];
    s += a.x * b.x + a.y * b.y + a.z * b.z + a.w * b.w;
  }
  #pragma unroll
  for (int off = 32; off > 0; off >>= 1) s += __shfl_down(s, off);
  if ((tid & 63) == 0) red[tid >> 6] = s;
  __syncthreads();
  if (tid == 0)
    atomicAdd(&fill_acc[j], red[0] + red[1] + red[2] + red[3]);
}

// stable member-list build, two-phase (1 barrier)
__global__ __launch_bounds__(1024) void k_scatter(
    const int* __restrict__ pred_x, const int* __restrict__ pred_t,
    int* __restrict__ idx_x, int* __restrict__ idx_t,
    int* __restrict__ count_x, int* __restrict__ count_t)
{
  const int c    = blockIdx.x >> 1;
  const int side = blockIdx.x & 1;
  const int* __restrict__ pred = side ? pred_t : pred_x;
  int* __restrict__ out = side ? idx_t : idx_x;
  int* __restrict__ cnt = side ? count_t : count_x;

  __shared__ int wsum[16];
  const int tid = threadIdx.x, lane = tid & 63, w = tid >> 6;
  const int beg = w * 4096;

  int cw = 0;
  for (int s = 0; s < 4096; s += 64) {
    const bool m = (pred[beg + s + lane] == c);
    cw += __popcll(__ballot(m));
  }
  if (lane == 0) wsum[w] = cw;
  __syncthreads();
  int base = 0, tot = 0;
  #pragma unroll
  for (int k = 0; k < 16; ++k) { int v = wsum[k]; tot += v; if (k < w) base += v; }

  int run = base;
  for (int s = 0; s < 4096; s += 64) {
    const int i = beg + s + lane;
    const bool m = (pred[i] == c);
    unsigned long long bal = __ballot(m);
    int lp = __popcll(bal & ((1ull << lane) - 1ull));
    if (m) { int pos = run + lp; if (pos < CAP) out[c * CAP + pos] = i; }
    run += __popcll(bal);
  }
  if (tid == 0) cnt[c] = tot;
}

__global__ __launch_bounds__(128) void k_offsets(
    const int* __restrict__ count_x, const int* __restrict__ count_t,
    int* __restrict__ offc)
{
  __shared__ int sm[128];
  const int tid = threadIdx.x;
  const int m  = min(min(count_x[tid], CAP), min(count_t[tid], CAP));
  const int sz = ((m + 3) & ~3) * DIM;
  sm[tid] = sz;
  __syncthreads();
  for (int s = 1; s < 128; s <<= 1) {
    int v = (tid >= s) ? sm[tid - s] : 0;
    __syncthreads();
    sm[tid] += v;
    __syncthreads();
  }
  offc[tid] = sm[tid] - sz;
}

// gather + transpose into coalesced column arenas (after k_fill: wmat dead)
__global__ __launch_bounds__(256) void k_gather_t(
    const float* __restrict__ x, const float* __restrict__ t,
    const int* __restrict__ idx_x, const int* __restrict__ idx_t,
    const int* __restrict__ count_x, const int* __restrict__ count_t,
    const int* __restrict__ offc,
    float* __restrict__ gxT, float* __restrict__ gtT)
{
  const int wid  = blockIdx.x * 4 + (threadIdx.x >> 6);
  const int lane = threadIdx.x & 63;
  const int side = wid >> 14;
  const int c    = (wid >> 7) & 127;
  const int q    = wid & 127;
  const int m = min(min(count_x[c], CAP), min(count_t[c], CAP));
  if (q * 64 >= m) return;
  const int r  = q * 64 + lane;
  const int mp = (m + 3) & ~3;
  const float* __restrict__ src = side ? t : x;
  const int*   __restrict__ idx = side ? idx_t : idx_x;
  float* __restrict__ dst = (side ? gtT : gxT) + offc[c];
  if (r < m) {
    const float4* rp =
        reinterpret_cast<const float4*>(src + (size_t)idx[c * CAP + r] * DIM);
    float v[DIM];
    #pragma unroll
    for (int qq = 0; qq < DIM / 4; ++qq) {
      float4 f = rp[qq];
      v[4*qq+0]=f.x; v[4*qq+1]=f.y; v[4*qq+2]=f.z; v[4*qq+3]=f.w;
    }
    #pragma unroll
    for (int d = 0; d < DIM; ++d) dst[(size_t)d * mp + r] = v[d];
  }
}

// ---- in-register bitonic helpers ----
__device__ __forceinline__ void ce(float& a, float& b, bool up) {
  float lo = fminf(a, b), hi = fmaxf(a, b);
  a = up ? lo : hi;
  b = up ? hi : lo;
}

__device__ __forceinline__ void merge8(float* v, bool up) {
  ce(v[0],v[4],up); ce(v[1],v[5],up); ce(v[2],v[6],up); ce(v[3],v[7],up);
  ce(v[0],v[2],up); ce(v[1],v[3],up); ce(v[4],v[6],up); ce(v[5],v[7],up);
  ce(v[0],v[1],up); ce(v[2],v[3],up); ce(v[4],v[5],up); ce(v[6],v[7],up);
}

__device__ __forceinline__ void sort8(float* v, bool up8) {
  ce(v[0],v[1],true );  ce(v[2],v[3],false); ce(v[4],v[5],true );  ce(v[6],v[7],false);
  ce(v[0],v[2],true );  ce(v[1],v[3],true );  ce(v[4],v[6],false); ce(v[5],v[7],false);
  ce(v[0],v[1],true );  ce(v[2],v[3],true );  ce(v[4],v[5],false); ce(v[6],v[7],false);
  merge8(v, up8);
}

__device__ __forceinline__ void merge16(float* v, bool up) {
  #pragma unroll
  for (int e = 0; e < 8; ++e) ce(v[e], v[e + 8], up);
  merge8(v, up);
  merge8(v + 8, up);
}

__device__ __forceinline__ void sort16(float* v, bool up16) {
  sort8(v, true);
  sort8(v + 8, false);
  merge16(v, up16);
}

__device__ __forceinline__ void stage_one8(float v[8], int ib, int k, bool up) {
  for (int j = (k >> 1) > 256 ? 256 : (k >> 1); j >= 8; j >>= 1) {
    const int  jl = j >> 3;
    const bool tm = (up == ((ib & j) == 0));
    #pragma unroll
    for (int e = 0; e < 8; ++e) {
      float p = __shfl_xor(v[e], jl, 64);
      v[e] = tm ? fminf(v[e], p) : fmaxf(v[e], p);
    }
  }
  merge8(v, up);
}

__device__ __forceinline__ void stage_one16(float v[16], int ib, int k, bool up) {
  #pragma unroll
  for (int j = (k >> 1) > 512 ? 512 : (k >> 1); j >= 16; j >>= 1) {
    const int  jl = j >> 4;
    const bool tm = (up == ((ib & j) == 0));
    #pragma unroll
    for (int e = 0; e < 16; ++e) {
      float p = __shfl_xor(v[e], jl, 64);
      v[e] = tm ? fminf(v[e], p) : fmaxf(v[e], p);
    }
  }
  merge16(v, up);
}

__device__ __forceinline__ void load8c(const float* __restrict__ col,
                                       int ib, int m, float v[8]) {
  if (ib + 7 < m) {
    #pragma unroll
    for (int q = 0; q < 2; ++q) {
      float4 f = *(const float4*)&col[ib + 4 * q];
      v[4*q+0]=f.x; v[4*q+1]=f.y; v[4*q+2]=f.z; v[4*q+3]=f.w;
    }
  } else {
    #pragma unroll
    for (int e = 0; e < 8; ++e) v[e] = (ib + e < m) ? col[ib + e] : INFINITY;
  }
}

__device__ __forceinline__ void load16c(const float* __restrict__ col,
                                        int ib, int m, float v[16]) {
  if (ib + 15 < m) {
    #pragma unroll
    for (int q = 0; q < 4; ++q) {
      float4 f = *(const float4*)&col[ib + 4 * q];
      v[4*q+0]=f.x; v[4*q+1]=f.y; v[4*q+2]=f.z; v[4*q+3]=f.w;
    }
  } else {
    #pragma unroll
    for (int e = 0; e < 16; ++e) v[e] = (ib + e < m) ? col[ib + e] : INFINITY;
  }
}

// full P-sort of one column; LDS only for j>=1024; compile-time P (no spill)
template<int P>
__device__ __forceinline__ void sort_col(float v[16], int ib, bool act,
                                         const float* __restrict__ col,
                                         int m, float* __restrict__ sa) {
  if (act) {
    load16c(col, ib, m, v);
    sort16(v, ((ib & 16) == 0));
    #pragma unroll
    for (int k = 32; k <= 1024; k <<= 1)
      stage_one16(v, ib, k, ((ib & k) == 0));
  }
  #pragma unroll
  for (int k = 2048; k <= P; k <<= 1) {
    const bool up = ((ib & k) == 0);
    #pragma unroll
    for (int j = k >> 1; j >= 1024; j >>= 1) {
      __syncthreads();
      if (act) {
        #pragma unroll
        for (int q = 0; q < 4; ++q)
          *(float4*)&sa[ib + 4*q] =
              make_float4(v[4*q], v[4*q+1], v[4*q+2], v[4*q+3]);
      }
      __syncthreads();
      if (act) {
        const int pi = ib ^ j;
        const bool tm = (up == ((ib & j) == 0));
        #pragma unroll
        for (int q = 0; q < 4; ++q) {
          float4 A = *(const float4*)&sa[pi + 4*q];
          v[4*q+0] = tm ? fminf(v[4*q+0],A.x) : fmaxf(v[4*q+0],A.x);
          v[4*q+1] = tm ? fminf(v[4*q+1],A.y) : fmaxf(v[4*q+1],A.y);
          v[4*q+2] = tm ? fminf(v[4*q+2],A.z) : fmaxf(v[4*q+2],A.z);
          v[4*q+3] = tm ? fminf(v[4*q+3],A.w) : fmaxf(v[4*q+3],A.w);
        }
      }
    }
    if (act) stage_one16(v, ib, k, up);
  }
}

template<int P>
__device__ __forceinline__ void sort_col_io(float* __restrict__ col,
                                            int m, int mp, int tid,
                                            float* __restrict__ sa) {
  const int ib = tid << 4;
  const bool act = (ib < P);
  float v[16];
  sort_col<P>(v, ib, act, col, m, sa);
  if (act) {
    #pragma unroll
    for (int q = 0; q < 4; ++q)
      if (ib + 4 * q < mp)
        *(float4*)&col[ib + 4*q] =
            make_float4(v[4*q], v[4*q+1], v[4*q+2], v[4*q+3]);
  }
}

// In-place column sort. Blocks [0,16384): one (side,c,d) task each for
// m>1024 -- A- and B-side sorts run in DIFFERENT blocks (2x task
// parallelism). Blocks [16384,18432): 8 wave-columns each (m<=1024,
// no barriers, adaptive P for m<=512).
__global__ __launch_bounds__(512) void k_sort(
    float* __restrict__ gxT, float* __restrict__ gtT,
    const int* __restrict__ offc,
    const int* __restrict__ count_x, const int* __restrict__ count_t)
{
  __shared__ float sa[8192];   // 32 KB (task role only)
  const int tid = threadIdx.x;

  if (blockIdx.x < 16384) {
    const int side = blockIdx.x >> 13;
    const int cd   = blockIdx.x & 8191;
    const int c = cd >> 6, d = cd & 63;
    const int m = min(min(count_x[c], CAP), min(count_t[c], CAP));
    if (m <= 1024) return;
    const int mp = (m + 3) & ~3;
    float* col = (side ? gtT : gxT) + offc[c] + (size_t)d * mp;
    if (m <= 2048)      sort_col_io<2048>(col, m, mp, tid, sa);
    else if (m <= 4096) sort_col_io<4096>(col, m, mp, tid, sa);
    else                sort_col_io<8192>(col, m, mp, tid, sa);
  } else {
    const int base = (blockIdx.x - 16384) * 8 + (tid >> 6);
    const int lane = tid & 63;
    const int side = base >> 13;
    const int cd   = base & 8191;
    const int c = cd >> 6, d = cd & 63;
    const int m = min(min(count_x[c], CAP), min(count_t[c], CAP));
    if (m > 1024 || m == 0) return;
    const int mp = (m + 3) & ~3;
    float* col = (side ? gtT : gxT) + offc[c] + (size_t)d * mp;

    if (m <= 512) {
      int P = 8;
      while (P < m) P <<= 1;
      const int ib = lane << 3;
      float v[8];
      load8c(col, ib, m, v);
      sort8(v, ((ib & 8) == 0));
      for (int k = 16; k <= P; k <<= 1)        // runtime bound: spill-safe
        stage_one8(v, ib, k, ((ib & k) == 0));
      #pragma unroll
      for (int q = 0; q < 2; ++q)
        if (ib + 4 * q < mp)
          *(float4*)&col[ib + 4*q] =
              make_float4(v[4*q], v[4*q+1], v[4*q+2], v[4*q+3]);
    } else {
      const int ib = lane << 4;
      float v[16];
      load16c(col, ib, m, v);
      sort16(v, ((ib & 16) == 0));
      #pragma unroll
      for (int k = 32; k <= 1024; k <<= 1)
        stage_one16(v, ib, k, ((ib & k) == 0));
      #pragma unroll
      for (int q = 0; q < 4; ++q)
        if (ib + 4 * q < mp)
          *(float4*)&col[ib + 4*q] =
              make_float4(v[4*q], v[4*q+1], v[4*q+2], v[4*q+3]);
    }
  }
}

// streaming |sorted(a)-sorted(b)| reduce per (c,d); covers m==0 slots too
__global__ __launch_bounds__(256) void k_diff(
    const float* __restrict__ gxT, const float* __restrict__ gtT,
    const int* __restrict__ offc,
    const int* __restrict__ count_x, const int* __restrict__ count_t,
    float* __restrict__ parts)
{
  __shared__ float red[4];
  const int task = blockIdx.x;
  const int c = task >> 6, d = task & 63;
  const int m = min(min(count_x[c], CAP), min(count_t[c], CAP));
  const int tid = threadIdx.x;
  if (m == 0) { if (tid == 0) parts[task] = 0.0f; return; }
  const int mp = (m + 3) & ~3;
  const float* colx = gxT + offc[c] + (size_t)d * mp;
  const float* colt = gtT + offc[c] + (size_t)d * mp;
  float s = 0.0f;
  for (int r = tid * 4; r < mp; r += 1024) {
    float4 a = *(const float4*)&colx[r];
    float4 b = *(const float4*)&colt[r];
    if (r + 3 < m) {
      s += fabsf(a.x-b.x) + fabsf(a.y-b.y) + fabsf(a.z-b.z) + fabsf(a.w-b.w);
    } else {
      if (r + 0 < m) s += fabsf(a.x - b.x);
      if (r + 1 < m) s += fabsf(a.y - b.y);
      if (r + 2 < m) s += fabsf(a.z - b.z);
      if (r + 3 < m) s += fabsf(a.w - b.w);
    }
  }
  #pragma unroll
  for (int off = 32; off > 0; off >>= 1) s += __shfl_down(s, off);
  if ((tid & 63) == 0) red[tid >> 6] = s;
  __syncthreads();
  if (tid == 0)
    parts[task] = (red[0] + red[1] + red[2] + red[3]) / (float)(m * DIM);
}

__global__ __launch_bounds__(1024) void k_final(
    const float* __restrict__ fill_acc, const float* __restrict__ ft,
    const float* __restrict__ parts, float* __restrict__ out)
{
  __shared__ float red[16];
  const int tid = threadIdx.x;
  float s = 0.0f;
  #pragma unroll
  for (int i = 0; i < 8; ++i) s += parts[tid + i * 1024];
  if (tid < K_CL) {
    float v = fill_acc[tid] * (1.0f / (float)N_PTS) - ft[tid];
    s += v * v * (1.0f / (float)K_CL);
  }
  #pragma unroll
  for (int off = 32; off > 0; off >>= 1) s += __shfl_down(s, off);
  if ((tid & 63) == 0) red[tid >> 6] = s;
  __syncthreads();
  if (tid == 0) {
    float tot = 0.0f;
    #pragma unroll
    for (int w = 0; w < 16; ++w) tot += red[w];
    out[0] = tot;
  }
}

extern "C" void kernel_launch(void* const* d_in, const int* in_sizes, int n_in,
                              void* d_out, int out_size, void* d_ws, size_t ws_size,
                              hipStream_t stream)
{
  (void)in_sizes; (void)n_in; (void)out_size; (void)ws_size;
  const float* x      = (const float*)d_in[0];
  const float* target = (const float*)d_in[1];
  const float* cc     = (const float*)d_in[2];
  const int*   pred_t = (const int*)d_in[3];
  const float* ft     = (const float*)d_in[4];
  float* out = (float*)d_out;

  char* ws = (char*)d_ws;
  float* fill_acc = (float*)(ws + 0);
  int*   pred_x   = (int*)(ws + 1024);
  int*   idx_x    = (int*)(ws + 263168);
  int*   idx_t    = (int*)(ws + 4457472);
  int*   count_x  = (int*)(ws + 8651776);
  int*   count_t  = (int*)(ws + 8651776 + 512);
  float* parts    = (float*)(ws + 8652800);
  float* sumw     = (float*)(ws + 8685568);
  float* inv_sumw = (float*)(ws + 8947712);
  unsigned long long* pred_enc = (unsigned long long*)(ws + 9209856);
  int*   offc     = (int*)(ws + 9734144);
  float* gxT      = (float*)(ws + 9735168);
  float* gtT      = (float*)(ws + 26643456);
  float* wmat     = (float*)(ws + 9735168);   // 32 MB, dead after k_fill;
                                              // overlays gxT+gtT only

  k_init<<<N_PTS / 256, 256, 0, stream>>>(fill_acc, sumw, pred_enc);
  k_dist1<<<N_PTS / 256 * 4, 256, 0, stream>>>(x, cc, sumw, pred_enc, wmat);
  k_pred<<<N_PTS / 256, 256, 0, stream>>>(pred_enc, sumw, pred_x, inv_sumw);
  k_fill<<<K_CL * 8, 256, 0, stream>>>(wmat, inv_sumw, fill_acc);
  k_scatter<<<K_CL * 2, 1024, 0, stream>>>(pred_x, pred_t, idx_x, idx_t,
                                           count_x, count_t);
  k_offsets<<<1, 128, 0, stream>>>(count_x, count_t, offc);
  k_gather_t<<<8192, 256, 0, stream>>>(x, target, idx_x, idx_t,
                                       count_x, count_t, offc, gxT, gtT);
  k_sort<<<16384 + 2048, 512, 0, stream>>>(gxT, gtT, offc, count_x, count_t);
  k_diff<<<K_CL * DIM, 256, 0, stream>>>(gxT, gtT, offc,
                                         count_x, count_t, parts);
  k_final<<<1, 1024, 0, stream>>>(fill_acc, ft, parts, out);
}